// Round 18
// baseline (80.086 us; speedup 1.0000x reference)
//
#include <hip/hip_runtime.h>
#include <hip/hip_bf16.h>

#define SEQ 2048
#define BHCOUNT 32
#define NROWS (BHCOUNT*SEQ)   /* 65536 rows of [64] */

typedef unsigned short u16;
typedef unsigned int u32;
using bf16x8 = __attribute__((ext_vector_type(8))) short;   // 8 bf16 = 4 VGPR
using f32x4  = __attribute__((ext_vector_type(4))) float;
using f32x16 = __attribute__((ext_vector_type(16))) float;

__device__ __forceinline__ float bf2f(u16 h) {
    return __uint_as_float(((u32)h) << 16);
}
__device__ __forceinline__ u16 f2bf(float f) {
    u32 u = __float_as_uint(f);
    u32 r = (u + 0x7FFFu + ((u >> 16) & 1u)) >> 16;
    return (u16)r;
}
// raw v_exp_f32 (2^x). Flushes tiny results to 0 — fine for softmax tails.
__device__ __forceinline__ float fexp2(float x) {
    float r; asm("v_exp_f32 %0, %1" : "=v"(r) : "v"(x)); return r;
}

// async global->LDS, 16B per lane. Global addr is PER-LANE, LDS dest is
// wave-uniform base + lane*16 (m104). Size must be a literal.
__device__ __forceinline__ void gload16(const u16* g, u16* l) {
    __builtin_amdgcn_global_load_lds(
        (const __attribute__((address_space(1))) u32*)g,
        (__attribute__((address_space(3))) u32*)l, 16, 0, 0);
}

__device__ __forceinline__ void cvt8(const float* src, float sc, u16* o) {
    float4 a = *(const float4*)src;
    float4 b = *(const float4*)(src + 4);
    o[0]=f2bf(a.x*sc); o[1]=f2bf(a.y*sc); o[2]=f2bf(a.z*sc); o[3]=f2bf(a.w*sc);
    o[4]=f2bf(b.x*sc); o[5]=f2bf(b.y*sc); o[6]=f2bf(b.z*sc); o[7]=f2bf(b.w*sc);
}

// ---------------------------------------------------------------------------
// Kernel 1: MFMA QKV projection (round-8 verified body) FUSED with wconv.
// Round 18: Vg kappa order changed for the 32x32 PV fragments:
//   Vg[bh][tile][d 64][kappa 64],
//   kappa -> kv:  kv = 16*(kappa>>4) + 4*((kappa>>3)&1) + 8*((kappa>>2)&1) + (kappa&3)
// (groups of 4 consecutive kappa map to 4 consecutive kv -> uint2 writes OK)
// ---------------------------------------------------------------------------
__global__ __launch_bounds__(256) void qkv_wconv_kernel(
    const float* __restrict__ x,
    const float* __restrict__ wq, const float* __restrict__ bq,
    const float* __restrict__ wk, const float* __restrict__ bk,
    const float* __restrict__ wv, const float* __restrict__ bv,
    const float* __restrict__ wo,
    u16* __restrict__ Q, u16* __restrict__ K, u16* __restrict__ Vg,
    u16* __restrict__ wob_t)
{
    __shared__ u16 xs[128*64];   // x tile bf16 swizzled; later vstage[64][128]
    __shared__ u16 ws[192*64];   // wq|wk|wv bf16, swizzled, qscale folded in wq
    __shared__ float bs[192];    // bq*qscale | bk | bv
    const int t = threadIdx.x;

    if (blockIdx.x >= 512) {     // ---- wconv part (block-uniform branch) ----
        int g = (blockIdx.x - 512)*256 + t;   // 131072 slots of 8 elems
        int tile = g >> 9, within = g & 511;
        int row = within >> 3, ks = within & 7;
        int cb = tile >> 4, kt = tile & 15;
        u16 o[8];
        cvt8(&wo[(size_t)(cb*64 + row)*1024 + kt*64 + ks*8], 1.f, o);
        *(uint4*)&wob_t[(size_t)g*8] = *(uint4*)o;
        return;
    }

    const int wid = t >> 6, lane = t & 63;
    const int ln = lane & 15, g4 = lane >> 4;
    const int blk = blockIdx.x;
    const int m0 = blk * 128;
    const int bh = blk >> 4;
    const int ktg0 = (blk & 15) * 2;
    const float qscale = 0.125f * 1.44269504f;

    #pragma unroll
    for (int c = 0; c < 6; ++c) {
        int slot = c*256 + t;
        int row = slot >> 3, ks = slot & 7;
        const float* wsrc = (c < 2) ? wq : (c < 4) ? wk : wv;
        float sc = (c < 2) ? qscale : 1.f;
        u16 o[8];
        cvt8(&wsrc[(row & 63)*64 + ks*8], sc, o);
        *(uint4*)&ws[row*64 + ((ks ^ (row & 7)) << 3)] = *(uint4*)o;
    }
    #pragma unroll
    for (int c = 0; c < 4; ++c) {
        int slot = c*256 + t;
        int row = slot >> 3, ks = slot & 7;
        u16 o[8];
        cvt8(&x[(size_t)(m0 + row)*64 + ks*8], 1.f, o);
        *(uint4*)&xs[row*64 + ((ks ^ (row & 7)) << 3)] = *(uint4*)o;
    }
    if (t < 192) {
        int p = t >> 6, e = t & 63;
        bs[t] = (p == 0) ? bq[e]*qscale : (p == 1) ? bk[e] : bv[e];
    }
    __syncthreads();

    bf16x8 af[2][2];
    #pragma unroll
    for (int mf = 0; mf < 2; ++mf)
        #pragma unroll
        for (int kf = 0; kf < 2; ++kf) {
            int arow = wid*32 + mf*16 + ln;
            af[mf][kf] = *(const bf16x8*)&xs[arow*64 + (((kf*4 + g4) ^ (arow & 7)) << 3)];
        }

    #pragma unroll
    for (int p = 0; p < 2; ++p) {
        bf16x8 bfr[4][2];
        #pragma unroll
        for (int nt = 0; nt < 4; ++nt)
            #pragma unroll
            for (int kf = 0; kf < 2; ++kf) {
                int brow = p*64 + nt*16 + ln;
                bfr[nt][kf] = *(const bf16x8*)&ws[brow*64 + (((kf*4 + g4) ^ (ln & 7)) << 3)];
            }
        f32x4 acc[2][4];
        #pragma unroll
        for (int mf = 0; mf < 2; ++mf)
            #pragma unroll
            for (int nt = 0; nt < 4; ++nt) acc[mf][nt] = (f32x4){0.f,0.f,0.f,0.f};
        #pragma unroll
        for (int kf = 0; kf < 2; ++kf)
            #pragma unroll
            for (int mf = 0; mf < 2; ++mf)
                #pragma unroll
                for (int nt = 0; nt < 4; ++nt)
                    acc[mf][nt] = __builtin_amdgcn_mfma_f32_16x16x32_bf16(
                        af[mf][kf], bfr[nt][kf], acc[mf][nt], 0, 0, 0);
        u16* dst = p ? K : Q;
        #pragma unroll
        for (int mf = 0; mf < 2; ++mf)
            #pragma unroll
            for (int nt = 0; nt < 4; ++nt) {
                float bv4 = bs[p*64 + nt*16 + ln];
                #pragma unroll
                for (int r = 0; r < 4; ++r)
                    dst[(size_t)(m0 + wid*32 + mf*16 + g4*4 + r)*64 + nt*16 + ln]
                        = f2bf(acc[mf][nt][r] + bv4);
            }
    }

    bf16x8 wvf[4][2];
    #pragma unroll
    for (int et = 0; et < 4; ++et)
        #pragma unroll
        for (int kf = 0; kf < 2; ++kf) {
            int brow = 128 + et*16 + ln;
            wvf[et][kf] = *(const bf16x8*)&ws[brow*64 + (((kf*4 + g4) ^ (ln & 7)) << 3)];
        }
    f32x4 vacc[4][2];
    #pragma unroll
    for (int et = 0; et < 4; ++et)
        #pragma unroll
        for (int st = 0; st < 2; ++st) vacc[et][st] = (f32x4){0.f,0.f,0.f,0.f};
    #pragma unroll
    for (int kf = 0; kf < 2; ++kf)
        #pragma unroll
        for (int et = 0; et < 4; ++et)
            #pragma unroll
            for (int st = 0; st < 2; ++st)
                vacc[et][st] = __builtin_amdgcn_mfma_f32_16x16x32_bf16(
                    wvf[et][kf], af[st][kf], vacc[et][st], 0, 0, 0);

    __syncthreads();
    u16* vstage = xs;
    #pragma unroll
    for (int et = 0; et < 4; ++et)
        #pragma unroll
        for (int st = 0; st < 2; ++st)
            #pragma unroll
            for (int r = 0; r < 4; ++r) {
                int e = et*16 + g4*4 + r;
                int s = wid*32 + st*16 + ln;
                vstage[e*128 + ((s + 2*e) & 127)] = f2bf(vacc[et][st][r] + bs[128 + e]);
            }
    __syncthreads();

    // write kappa-permuted tiles (NEW 32x32 kappa order):
    //   kv = (kp0&48) + 4*((kp0>>3)&1) + 8*((kp0>>2)&1) + i   for i=0..3
    #pragma unroll
    for (int c = 0; c < 8; ++c) {
        int j = c*256 + t;
        int kt2 = j >> 10, within = j & 1023;
        int ee = within >> 4, kp0 = (within & 15) * 4;
        int sbase = (kp0 & 48) + (((kp0 >> 3) & 1) << 2) + (((kp0 >> 2) & 1) << 3);
        u16 o[4];
        #pragma unroll
        for (int i = 0; i < 4; ++i)
            o[i] = vstage[ee*128 + ((kt2*64 + sbase + i + 2*ee) & 127)];
        *(uint2*)&Vg[((size_t)bh*32 + ktg0 + kt2)*4096 + ee*64 + kp0] = *(uint2*)o;
    }
}

// ---------------------------------------------------------------------------
// Kernel 2: MFMA flash attention, 32x32x16 fragments, swapped-QK^T.
// Round 18: halves LDS reads per FLOP (16 b128 reads -> 20 MFMA of 32x32
// per wave per kv-tile, vs 16 reads -> 18 MFMA of 16x16).
// Block = 2 waves x 32 q-rows = 64 rows; grid (32,32) = 4 blocks/CU,
// 32KB double-buffered LDS, 4 independent barrier domains.
// Lane (l31 = lane&31, h = lane>>5):
//   swapped QK^T: sacc[nt] reg r = S[q=l31][kv = 32nt + (r&3)+8*(r>>2)+4h]
//     (C/D row formula HW-verified: m74/m101)
//   PV A-frag slot j of chunk c: kv = 16c + 4h + (j&3)+8*(j>>2)
//     == sacc[c>>1] regs (c&1)*8 + j  -> PURE IN-LANE repack (no shfl),
//     valid because fixed-base softmax (r14) needs no row reductions.
//   Vg kappa order matches this slot map (baked in qkv above).
//   A/B same-fill => QK^T and PV contraction layout-invariant.
// ---------------------------------------------------------------------------
__global__ __launch_bounds__(128, 2) void attn_kernel(
    const u16* __restrict__ Q, const u16* __restrict__ K,
    const u16* __restrict__ Vg, u16* __restrict__ ctx)
{
    __shared__ u16 Kls[2][4096];
    __shared__ u16 Vls[2][4096];

    const int t = threadIdx.x;          // 0..127
    const int wid = t >> 6, lane = t & 63;
    const int l31 = lane & 31, h = lane >> 5;
    const int bh = blockIdx.y;
    const size_t base   = (size_t)bh * SEQ * 64;
    const size_t vgbase = (size_t)bh * 32 * 4096;
    const int q0 = blockIdx.x * 64 + wid * 32;

    // staging: 512 slots of 16B per 64x64 tile; thread t stages slots c*128+t
    int goff[4];
    #pragma unroll
    for (int c = 0; c < 4; ++c) {
        int s = c*128 + t;
        int row = s >> 3, ks = s & 7;
        goff[c] = row*64 + ((ks ^ (row & 7)) << 3);
    }
    // LDS dest base for chunk c: element c*1024 + wid*512 (+ lane*8 by HW)

    // fragment offsets: foff[a][b]: row = a*32 + l31, ks = b*2 + h
    // K frag (nt,kc) -> foff[nt][kc];  V frag (c,dt) -> foff[dt][c]
    int foff[2][4];
    #pragma unroll
    for (int a = 0; a < 2; ++a)
        #pragma unroll
        for (int b = 0; b < 4; ++b) {
            int row = a*32 + l31;
            foff[a][b] = row*64 + (((b*2 + h) ^ (row & 7)) << 3);
        }

    // Q fragments (B-operand): lane holds Q[q0+l31][kc*16 + h*8 .. +8]
    bf16x8 qf[4];
    #pragma unroll
    for (int kc = 0; kc < 4; ++kc)
        qf[kc] = *(const bf16x8*)&Q[base + (size_t)(q0 + l31)*64 + kc*16 + h*8];

    bf16x8 ones;
    #pragma unroll
    for (int i = 0; i < 8; ++i) ones[i] = (short)0x3F80;   // bf16 1.0

    f32x16 oacc0, oacc1, lacc;
    #pragma unroll
    for (int i = 0; i < 16; ++i) { oacc0[i] = 0.f; oacc1[i] = 0.f; lacc[i] = 0.f; }

    // prologue: stage tile 0 into buf 0
    #pragma unroll
    for (int c = 0; c < 4; ++c) {
        gload16(&K [base   + goff[c]], &Kls[0][c*1024 + wid*512]);
        gload16(&Vg[vgbase + goff[c]], &Vls[0][c*1024 + wid*512]);
    }
    __syncthreads();

    for (int kt2 = 0; kt2 < 16; ++kt2) {
        #pragma unroll
        for (int half = 0; half < 2; ++half) {
            const int kt = kt2*2 + half;
            if (kt < 31) {   // issue next tile's async loads into other buffer
                #pragma unroll
                for (int c = 0; c < 4; ++c) {
                    gload16(&K [base   + (size_t)(kt+1)*4096 + goff[c]],
                            &Kls[half^1][c*1024 + wid*512]);
                    gload16(&Vg[vgbase + (size_t)(kt+1)*4096 + goff[c]],
                            &Vls[half^1][c*1024 + wid*512]);
                }
            }
            const u16* Ks  = Kls[half];
            const u16* Vts = Vls[half];

            // QK^T: sacc[nt] over kv chunk of 32, contracted over 4 k-chunks
            f32x16 s0, s1;
            #pragma unroll
            for (int i = 0; i < 16; ++i) { s0[i] = 0.f; s1[i] = 0.f; }
            __builtin_amdgcn_s_setprio(1);
            #pragma unroll
            for (int kc = 0; kc < 4; ++kc)
                s0 = __builtin_amdgcn_mfma_f32_32x32x16_bf16(
                    *(const bf16x8*)&Ks[foff[0][kc]], qf[kc], s0, 0, 0, 0);
            #pragma unroll
            for (int kc = 0; kc < 4; ++kc)
                s1 = __builtin_amdgcn_mfma_f32_32x32x16_bf16(
                    *(const bf16x8*)&Ks[foff[1][kc]], qf[kc], s1, 0, 0, 0);
            __builtin_amdgcn_s_setprio(0);

            // softmax, fixed base m = 0 (r14-verified)
            #pragma unroll
            for (int i = 0; i < 16; ++i) { s0[i] = fexp2(s0[i]); s1[i] = fexp2(s1[i]); }

            // in-lane repack into PV A-frags: pf[c] = sacc[c>>1] regs (c&1)*8..+7
            union PU { u32 w[4]; bf16x8 v; } p0, p1, p2, p3;
            asm("v_cvt_pk_bf16_f32 %0, %1, %2" : "=v"(p0.w[0]) : "v"(s0[0]),  "v"(s0[1]));
            asm("v_cvt_pk_bf16_f32 %0, %1, %2" : "=v"(p0.w[1]) : "v"(s0[2]),  "v"(s0[3]));
            asm("v_cvt_pk_bf16_f32 %0, %1, %2" : "=v"(p0.w[2]) : "v"(s0[4]),  "v"(s0[5]));
            asm("v_cvt_pk_bf16_f32 %0, %1, %2" : "=v"(p0.w[3]) : "v"(s0[6]),  "v"(s0[7]));
            asm("v_cvt_pk_bf16_f32 %0, %1, %2" : "=v"(p1.w[0]) : "v"(s0[8]),  "v"(s0[9]));
            asm("v_cvt_pk_bf16_f32 %0, %1, %2" : "=v"(p1.w[1]) : "v"(s0[10]), "v"(s0[11]));
            asm("v_cvt_pk_bf16_f32 %0, %1, %2" : "=v"(p1.w[2]) : "v"(s0[12]), "v"(s0[13]));
            asm("v_cvt_pk_bf16_f32 %0, %1, %2" : "=v"(p1.w[3]) : "v"(s0[14]), "v"(s0[15]));
            asm("v_cvt_pk_bf16_f32 %0, %1, %2" : "=v"(p2.w[0]) : "v"(s1[0]),  "v"(s1[1]));
            asm("v_cvt_pk_bf16_f32 %0, %1, %2" : "=v"(p2.w[1]) : "v"(s1[2]),  "v"(s1[3]));
            asm("v_cvt_pk_bf16_f32 %0, %1, %2" : "=v"(p2.w[2]) : "v"(s1[4]),  "v"(s1[5]));
            asm("v_cvt_pk_bf16_f32 %0, %1, %2" : "=v"(p2.w[3]) : "v"(s1[6]),  "v"(s1[7]));
            asm("v_cvt_pk_bf16_f32 %0, %1, %2" : "=v"(p3.w[0]) : "v"(s1[8]),  "v"(s1[9]));
            asm("v_cvt_pk_bf16_f32 %0, %1, %2" : "=v"(p3.w[1]) : "v"(s1[10]), "v"(s1[11]));
            asm("v_cvt_pk_bf16_f32 %0, %1, %2" : "=v"(p3.w[2]) : "v"(s1[12]), "v"(s1[13]));
            asm("v_cvt_pk_bf16_f32 %0, %1, %2" : "=v"(p3.w[3]) : "v"(s1[14]), "v"(s1[15]));
            bf16x8 pf[4] = { p0.v, p1.v, p2.v, p3.v };

            // PV + l-sum (ones-column)
            __builtin_amdgcn_s_setprio(1);
            #pragma unroll
            for (int c = 0; c < 4; ++c) {
                oacc0 = __builtin_amdgcn_mfma_f32_32x32x16_bf16(
                    pf[c], *(const bf16x8*)&Vts[foff[0][c]], oacc0, 0, 0, 0);
                oacc1 = __builtin_amdgcn_mfma_f32_32x32x16_bf16(
                    pf[c], *(const bf16x8*)&Vts[foff[1][c]], oacc1, 0, 0, 0);
                lacc  = __builtin_amdgcn_mfma_f32_32x32x16_bf16(
                    pf[c], ones, lacc, 0, 0, 0);
            }
            __builtin_amdgcn_s_setprio(0);

            __syncthreads();   // drains my async loads; publishes tile kt+1
        }
    }

    // epilogue: lane holds O[q=(r&3)+8*(r>>2)+4h][d = dt*32 + l31]
    #pragma unroll
    for (int r = 0; r < 16; ++r) {
        int q = (r & 3) + 8*(r >> 2) + 4*h;
        float inv = 1.f / lacc[r];
        size_t row = base + (size_t)(q0 + q)*64;
        ctx[row + l31]      = f2bf(oacc0[r] * inv);
        ctx[row + 32 + l31] = f2bf(oacc1[r] * inv);
    }
}

// ---------------------------------------------------------------------------
// Kernel 3: MFMA output projection (flat-reshape A — round-4 lesson;
// async gload16 double-buffered staging — round-15 verified).
// ---------------------------------------------------------------------------
__global__ __launch_bounds__(256) void oproj_kernel(
    const u16* __restrict__ ctx, const u16* __restrict__ wob_t,
    const float* __restrict__ bo, float* __restrict__ out)
{
    __shared__ u16 Als[2][128*64];   // [buf][m][k], swizzled via source
    __shared__ u16 Bls[2][64*64];    // [buf][n][k], swizzled via source
    const int t = threadIdx.x;
    const int wid = t >> 6, lane = t & 63;
    const int ln = lane & 15, g4 = lane >> 4;
    const int wr = wid >> 1, wc = wid & 1;
    const int rb = blockIdx.x, cb = blockIdx.y;
    const int m0 = rb * 128;

    int gA[4], gB[2];
    #pragma unroll
    for (int c = 0; c < 4; ++c) {
        int slot = c*256 + t;
        int row = slot >> 3, ks = slot & 7;
        gA[c] = row*1024 + ((ks ^ (row & 7)) << 3);
    }
    #pragma unroll
    for (int c = 0; c < 2; ++c) {
        int slot = c*256 + t;
        int row = slot >> 3, ks = slot & 7;
        gB[c] = row*64 + ((ks ^ (row & 7)) << 3);
    }
    const u16* actx = ctx + (size_t)m0*1024;
    const u16* bw   = wob_t + (size_t)cb*16*4096;

    f32x4 acc[4][2];
    #pragma unroll
    for (int mf = 0; mf < 4; ++mf)
        #pragma unroll
        for (int nf = 0; nf < 2; ++nf)
            acc[mf][nf] = (f32x4){0.f, 0.f, 0.f, 0.f};

    #pragma unroll
    for (int c = 0; c < 4; ++c) gload16(&actx[gA[c]], &Als[0][(c*256+t)*8]);
    #pragma unroll
    for (int c = 0; c < 2; ++c) gload16(&bw[gB[c]],   &Bls[0][(c*256+t)*8]);
    __syncthreads();

    for (int kt2 = 0; kt2 < 8; ++kt2) {
        #pragma unroll
        for (int half = 0; half < 2; ++half) {
            const int kt = kt2*2 + half;
            if (kt < 15) {
                #pragma unroll
                for (int c = 0; c < 4; ++c)
                    gload16(&actx[(kt+1)*64 + gA[c]], &Als[half^1][(c*256+t)*8]);
                #pragma unroll
                for (int c = 0; c < 2; ++c)
                    gload16(&bw[(kt+1)*4096 + gB[c]], &Bls[half^1][(c*256+t)*8]);
            }
            const u16* As = Als[half];
            const u16* Bs = Bls[half];

            __builtin_amdgcn_s_setprio(1);
            #pragma unroll
            for (int kf = 0; kf < 2; ++kf) {
                bf16x8 af[4], bfr[2];
                #pragma unroll
                for (int mf = 0; mf < 4; ++mf) {
                    int arow = wr*64 + mf*16 + ln;
                    af[mf] = *(const bf16x8*)&As[arow*64 + (((kf*4 + g4) ^ (arow & 7)) << 3)];
                }
                #pragma unroll
                for (int nf = 0; nf < 2; ++nf) {
                    int brow = wc*32 + nf*16 + ln;
                    bfr[nf] = *(const bf16x8*)&Bs[brow*64 + (((kf*4 + g4) ^ (brow & 7)) << 3)];
                }
                #pragma unroll
                for (int mf = 0; mf < 4; ++mf)
                    #pragma unroll
                    for (int nf = 0; nf < 2; ++nf)
                        acc[mf][nf] = __builtin_amdgcn_mfma_f32_16x16x32_bf16(
                            af[mf], bfr[nf], acc[mf][nf], 0, 0, 0);
            }
            __builtin_amdgcn_s_setprio(0);

            __syncthreads();
        }
    }

    #pragma unroll
    for (int mf = 0; mf < 4; ++mf)
        #pragma unroll
        for (int r = 0; r < 4; ++r) {
            int m = m0 + wr*64 + mf*16 + g4*4 + r;
            #pragma unroll
            for (int nf = 0; nf < 2; ++nf) {
                int col = cb*64 + wc*32 + nf*16 + ln;
                out[(size_t)m*1024 + col] = acc[mf][nf][r] + bo[col];
            }
        }
}

extern "C" void kernel_launch(void* const* d_in, const int* in_sizes, int n_in,
                              void* d_out, int out_size, void* d_ws, size_t ws_size,
                              hipStream_t stream) {
    (void)in_sizes; (void)n_in; (void)out_size; (void)ws_size;
    const float* x  = (const float*)d_in[0];
    const float* wq = (const float*)d_in[1];
    const float* bq = (const float*)d_in[2];
    const float* wk = (const float*)d_in[3];
    const float* bk = (const float*)d_in[4];
    const float* wv = (const float*)d_in[5];
    const float* bv = (const float*)d_in[6];
    const float* wo = (const float*)d_in[7];
    const float* bo = (const float*)d_in[8];
    float* out = (float*)d_out;

    u16* Qb  = (u16*)d_ws;
    u16* Kb  = Qb + (size_t)NROWS*64;
    u16* Vgb = Kb + (size_t)NROWS*64;
    u16* ctx = Vgb + (size_t)NROWS*64;
    u16* wob_t = ctx + (size_t)NROWS*64;

    qkv_wconv_kernel<<<dim3(1024), 256, 0, stream>>>(
        x, wq, bq, wk, bk, wv, bv, wo, Qb, Kb, Vgb, wob_t);
    attn_kernel<<<dim3(32, 32), 128, 0, stream>>>(Qb, Kb, Vgb, ctx);
    oproj_kernel<<<dim3(32, 16), 256, 0, stream>>>(ctx, wob_t, bo, out);
}

// Round 19
// 70.097 us; speedup vs baseline: 1.1425x; 1.1425x over previous
//
#include <hip/hip_runtime.h>
#include <hip/hip_bf16.h>

#define SEQ 2048
#define BHCOUNT 32
#define NROWS (BHCOUNT*SEQ)   /* 65536 rows of [64] */

typedef unsigned short u16;
typedef unsigned int u32;
using bf16x8 = __attribute__((ext_vector_type(8))) short;   // 8 bf16 = 4 VGPR
using f32x4  = __attribute__((ext_vector_type(4))) float;

__device__ __forceinline__ float bf2f(u16 h) {
    return __uint_as_float(((u32)h) << 16);
}
__device__ __forceinline__ u16 f2bf(float f) {
    u32 u = __float_as_uint(f);
    u32 r = (u + 0x7FFFu + ((u >> 16) & 1u)) >> 16;
    return (u16)r;
}
// raw v_exp_f32 (2^x). Flushes tiny results to 0 — fine for softmax tails.
__device__ __forceinline__ float fexp2(float x) {
    float r; asm("v_exp_f32 %0, %1" : "=v"(r) : "v"(x)); return r;
}

// async global->LDS, 16B per lane. Global addr is PER-LANE, LDS dest is
// wave-uniform base + lane*16 (m104). Size must be a literal.
__device__ __forceinline__ void gload16(const u16* g, u16* l) {
    __builtin_amdgcn_global_load_lds(
        (const __attribute__((address_space(1))) u32*)g,
        (__attribute__((address_space(3))) u32*)l, 16, 0, 0);
}

__device__ __forceinline__ void cvt8(const float* src, float sc, u16* o) {
    float4 a = *(const float4*)src;
    float4 b = *(const float4*)(src + 4);
    o[0]=f2bf(a.x*sc); o[1]=f2bf(a.y*sc); o[2]=f2bf(a.z*sc); o[3]=f2bf(a.w*sc);
    o[4]=f2bf(b.x*sc); o[5]=f2bf(b.y*sc); o[6]=f2bf(b.z*sc); o[7]=f2bf(b.w*sc);
}

// ---------------------------------------------------------------------------
// Kernel 1: MFMA QKV projection (round-8 verified body) FUSED with wconv.
// Vg kappa order: the 16x16 mapping (rounds 5-17, verified):
//   kv = 16*nt + 4*g4 + r  <->  kappa = 32*(nt&1) + 8*g4 + 4*(nt>>1) + r
// ---------------------------------------------------------------------------
__global__ __launch_bounds__(256) void qkv_wconv_kernel(
    const float* __restrict__ x,
    const float* __restrict__ wq, const float* __restrict__ bq,
    const float* __restrict__ wk, const float* __restrict__ bk,
    const float* __restrict__ wv, const float* __restrict__ bv,
    const float* __restrict__ wo,
    u16* __restrict__ Q, u16* __restrict__ K, u16* __restrict__ Vg,
    u16* __restrict__ wob_t)
{
    __shared__ u16 xs[128*64];   // x tile bf16 swizzled; later vstage[64][128]
    __shared__ u16 ws[192*64];   // wq|wk|wv bf16, swizzled, qscale folded in wq
    __shared__ float bs[192];    // bq*qscale | bk | bv
    const int t = threadIdx.x;

    if (blockIdx.x >= 512) {     // ---- wconv part (block-uniform branch) ----
        int g = (blockIdx.x - 512)*256 + t;   // 131072 slots of 8 elems
        int tile = g >> 9, within = g & 511;
        int row = within >> 3, ks = within & 7;
        int cb = tile >> 4, kt = tile & 15;
        u16 o[8];
        cvt8(&wo[(size_t)(cb*64 + row)*1024 + kt*64 + ks*8], 1.f, o);
        *(uint4*)&wob_t[(size_t)g*8] = *(uint4*)o;
        return;
    }

    const int wid = t >> 6, lane = t & 63;
    const int ln = lane & 15, g4 = lane >> 4;
    const int blk = blockIdx.x;
    const int m0 = blk * 128;
    const int bh = blk >> 4;
    const int ktg0 = (blk & 15) * 2;
    const float qscale = 0.125f * 1.44269504f;

    #pragma unroll
    for (int c = 0; c < 6; ++c) {
        int slot = c*256 + t;
        int row = slot >> 3, ks = slot & 7;
        const float* wsrc = (c < 2) ? wq : (c < 4) ? wk : wv;
        float sc = (c < 2) ? qscale : 1.f;
        u16 o[8];
        cvt8(&wsrc[(row & 63)*64 + ks*8], sc, o);
        *(uint4*)&ws[row*64 + ((ks ^ (row & 7)) << 3)] = *(uint4*)o;
    }
    #pragma unroll
    for (int c = 0; c < 4; ++c) {
        int slot = c*256 + t;
        int row = slot >> 3, ks = slot & 7;
        u16 o[8];
        cvt8(&x[(size_t)(m0 + row)*64 + ks*8], 1.f, o);
        *(uint4*)&xs[row*64 + ((ks ^ (row & 7)) << 3)] = *(uint4*)o;
    }
    if (t < 192) {
        int p = t >> 6, e = t & 63;
        bs[t] = (p == 0) ? bq[e]*qscale : (p == 1) ? bk[e] : bv[e];
    }
    __syncthreads();

    bf16x8 af[2][2];
    #pragma unroll
    for (int mf = 0; mf < 2; ++mf)
        #pragma unroll
        for (int kf = 0; kf < 2; ++kf) {
            int arow = wid*32 + mf*16 + ln;
            af[mf][kf] = *(const bf16x8*)&xs[arow*64 + (((kf*4 + g4) ^ (arow & 7)) << 3)];
        }

    #pragma unroll
    for (int p = 0; p < 2; ++p) {
        bf16x8 bfr[4][2];
        #pragma unroll
        for (int nt = 0; nt < 4; ++nt)
            #pragma unroll
            for (int kf = 0; kf < 2; ++kf) {
                int brow = p*64 + nt*16 + ln;
                bfr[nt][kf] = *(const bf16x8*)&ws[brow*64 + (((kf*4 + g4) ^ (ln & 7)) << 3)];
            }
        f32x4 acc[2][4];
        #pragma unroll
        for (int mf = 0; mf < 2; ++mf)
            #pragma unroll
            for (int nt = 0; nt < 4; ++nt) acc[mf][nt] = (f32x4){0.f,0.f,0.f,0.f};
        #pragma unroll
        for (int kf = 0; kf < 2; ++kf)
            #pragma unroll
            for (int mf = 0; mf < 2; ++mf)
                #pragma unroll
                for (int nt = 0; nt < 4; ++nt)
                    acc[mf][nt] = __builtin_amdgcn_mfma_f32_16x16x32_bf16(
                        af[mf][kf], bfr[nt][kf], acc[mf][nt], 0, 0, 0);
        u16* dst = p ? K : Q;
        #pragma unroll
        for (int mf = 0; mf < 2; ++mf)
            #pragma unroll
            for (int nt = 0; nt < 4; ++nt) {
                float bv4 = bs[p*64 + nt*16 + ln];
                #pragma unroll
                for (int r = 0; r < 4; ++r)
                    dst[(size_t)(m0 + wid*32 + mf*16 + g4*4 + r)*64 + nt*16 + ln]
                        = f2bf(acc[mf][nt][r] + bv4);
            }
    }

    bf16x8 wvf[4][2];
    #pragma unroll
    for (int et = 0; et < 4; ++et)
        #pragma unroll
        for (int kf = 0; kf < 2; ++kf) {
            int brow = 128 + et*16 + ln;
            wvf[et][kf] = *(const bf16x8*)&ws[brow*64 + (((kf*4 + g4) ^ (ln & 7)) << 3)];
        }
    f32x4 vacc[4][2];
    #pragma unroll
    for (int et = 0; et < 4; ++et)
        #pragma unroll
        for (int st = 0; st < 2; ++st) vacc[et][st] = (f32x4){0.f,0.f,0.f,0.f};
    #pragma unroll
    for (int kf = 0; kf < 2; ++kf)
        #pragma unroll
        for (int et = 0; et < 4; ++et)
            #pragma unroll
            for (int st = 0; st < 2; ++st)
                vacc[et][st] = __builtin_amdgcn_mfma_f32_16x16x32_bf16(
                    wvf[et][kf], af[st][kf], vacc[et][st], 0, 0, 0);

    __syncthreads();
    u16* vstage = xs;
    #pragma unroll
    for (int et = 0; et < 4; ++et)
        #pragma unroll
        for (int st = 0; st < 2; ++st)
            #pragma unroll
            for (int r = 0; r < 4; ++r) {
                int e = et*16 + g4*4 + r;
                int s = wid*32 + st*16 + ln;
                vstage[e*128 + ((s + 2*e) & 127)] = f2bf(vacc[et][st][r] + bs[128 + e]);
            }
    __syncthreads();

    // write kappa-permuted tiles (16x16 order, rounds 5-17 verified)
    #pragma unroll
    for (int c = 0; c < 8; ++c) {
        int j = c*256 + t;
        int kt2 = j >> 10, within = j & 1023;
        int ee = within >> 4, kp0 = (within & 15) * 4;
        int sbase = ((kp0 & 4) << 3) | ((kp0 & 32) >> 1) | ((kp0 & 24) >> 1);
        u16 o[4];
        #pragma unroll
        for (int i = 0; i < 4; ++i)
            o[i] = vstage[ee*128 + ((kt2*64 + sbase + i + 2*ee) & 127)];
        *(uint2*)&Vg[((size_t)bh*32 + ktg0 + kt2)*4096 + ee*64 + kp0] = *(uint2*)o;
    }
}

// ---------------------------------------------------------------------------
// Kernel 2: MFMA flash attention, swapped-QK^T, 16x16 frags.
// Round 19: kv-split x q-reuse. 512-thr block = 2 kv-halves (hk) x 4 waves
// (w4) x 32 q-rows. Waves of half hk process kv tiles hk*16..hk*16+15 on the
// SAME 128 q-rows, each K/V fragment read feeds 2 MFMAs (r16 body, verified).
// Total ds_read_b128 count HALVES vs r14/r17 while occupancy stays 16
// waves/CU (2 blocks x 8 waves): escapes the LDS-read-throughput wall
// (r17 arithmetic: 64 reads x 12cyc = 768 of 806 cyc/block-iter).
// Fixed-base softmax (r14) makes kv-partials merge by PURE ADDITION:
// in-block epilogue via repurposed LDS: O = O0+O1, l = l0+l1, divide, store.
// ---------------------------------------------------------------------------
__global__ __launch_bounds__(512, 4) void attn_kernel(
    const u16* __restrict__ Q, const u16* __restrict__ K,
    const u16* __restrict__ Vg, u16* __restrict__ ctx)
{
    __shared__ u16 Kls[2][2][4096];   // [kvhalf][buf][tile]
    __shared__ u16 Vls[2][2][4096];

    const int t = threadIdx.x;          // 0..511
    const int wid = t >> 6, lane = t & 63;
    const int hk = wid >> 2;            // kv half: 0 or 1
    const int w4 = wid & 3;             // wave within half
    const int tt = t & 255;             // thread within half
    const int ln = lane & 15, g4 = lane >> 4;
    const int bh = blockIdx.y;
    const size_t base   = (size_t)bh * SEQ * 64;
    const size_t vgbase = (size_t)bh * 32 * 4096;
    const int q0 = blockIdx.x * 128 + w4 * 32;
    const int kt0 = hk * 16;            // this half's first kv tile

    // staging: 512 slots of 16B per 64x64 tile, spread over this half's
    // 256 threads; thread tt stages slots tt and tt+256.
    int goff[2];
    #pragma unroll
    for (int c = 0; c < 2; ++c) {
        int s = c*256 + tt;
        int row = s >> 3, ks = s & 7;
        goff[c] = row*64 + ((ks ^ (row & 7)) << 3);
    }
    // LDS dest for chunk c: element c*2048 + w4*512 within [hk][buf]

    int foff[4][2];
    #pragma unroll
    for (int nt = 0; nt < 4; ++nt)
        #pragma unroll
        for (int kf = 0; kf < 2; ++kf) {
            int frow = nt*16 + ln;
            foff[nt][kf] = frow*64 + (((kf*4 + g4) ^ (frow & 7)) << 3);
        }

    // Q fragments for BOTH q-tiles (B-operand of swapped QK^T)
    bf16x8 qf0[2], qf1[2];
    #pragma unroll
    for (int kf = 0; kf < 2; ++kf) {
        qf0[kf] = *(const bf16x8*)&Q[base + (size_t)(q0 + ln)*64      + kf*32 + g4*8];
        qf1[kf] = *(const bf16x8*)&Q[base + (size_t)(q0 + 16 + ln)*64 + kf*32 + g4*8];
    }

    bf16x8 ones;
    #pragma unroll
    for (int i = 0; i < 8; ++i) ones[i] = (short)0x3F80;   // bf16 1.0

    f32x4 oacc0[4], oacc1[4];
    #pragma unroll
    for (int i = 0; i < 4; ++i) {
        oacc0[i] = (f32x4){0.f, 0.f, 0.f, 0.f};
        oacc1[i] = (f32x4){0.f, 0.f, 0.f, 0.f};
    }
    f32x4 lacc0 = (f32x4){0.f, 0.f, 0.f, 0.f};
    f32x4 lacc1 = (f32x4){0.f, 0.f, 0.f, 0.f};

    // prologue: stage this half's tile kt0 into buf 0
    #pragma unroll
    for (int c = 0; c < 2; ++c) {
        gload16(&K [base   + (size_t)kt0*4096 + goff[c]], &Kls[hk][0][c*2048 + w4*512]);
        gload16(&Vg[vgbase + (size_t)kt0*4096 + goff[c]], &Vls[hk][0][c*2048 + w4*512]);
    }
    __syncthreads();

    for (int kt2 = 0; kt2 < 8; ++kt2) {
        #pragma unroll
        for (int pb = 0; pb < 2; ++pb) {
            const int kt = kt2*2 + pb;
            if (kt < 15) {   // issue next tile's async loads into other buffer
                #pragma unroll
                for (int c = 0; c < 2; ++c) {
                    gload16(&K [base   + (size_t)(kt0+kt+1)*4096 + goff[c]],
                            &Kls[hk][pb^1][c*2048 + w4*512]);
                    gload16(&Vg[vgbase + (size_t)(kt0+kt+1)*4096 + goff[c]],
                            &Vls[hk][pb^1][c*2048 + w4*512]);
                }
            }
            const u16* Ks  = Kls[hk][pb];
            const u16* Vts = Vls[hk][pb];

            // QK^T for both q-tiles, each K fragment read once
            f32x4 s0[4], s1[4];
            #pragma unroll
            for (int nt = 0; nt < 4; ++nt) {
                s0[nt] = (f32x4){0.f, 0.f, 0.f, 0.f};
                s1[nt] = (f32x4){0.f, 0.f, 0.f, 0.f};
            }
            __builtin_amdgcn_s_setprio(1);
            #pragma unroll
            for (int nt = 0; nt < 4; ++nt)
                #pragma unroll
                for (int kf = 0; kf < 2; ++kf) {
                    bf16x8 kfr = *(const bf16x8*)&Ks[foff[nt][kf]];
                    s0[nt] = __builtin_amdgcn_mfma_f32_16x16x32_bf16(kfr, qf0[kf], s0[nt], 0, 0, 0);
                    s1[nt] = __builtin_amdgcn_mfma_f32_16x16x32_bf16(kfr, qf1[kf], s1[nt], 0, 0, 0);
                }
            __builtin_amdgcn_s_setprio(0);

            // softmax, fixed base m = 0 (r14-verified)
            #pragma unroll
            for (int nt = 0; nt < 4; ++nt)
                #pragma unroll
                for (int r = 0; r < 4; ++r) {
                    s0[nt][r] = fexp2(s0[nt][r]);
                    s1[nt][r] = fexp2(s1[nt][r]);
                }

            union PU { u32 w[4]; bf16x8 v; } a0, a1, b0, b1;
            asm("v_cvt_pk_bf16_f32 %0, %1, %2" : "=v"(a0.w[0]) : "v"(s0[0][0]), "v"(s0[0][1]));
            asm("v_cvt_pk_bf16_f32 %0, %1, %2" : "=v"(a0.w[1]) : "v"(s0[0][2]), "v"(s0[0][3]));
            asm("v_cvt_pk_bf16_f32 %0, %1, %2" : "=v"(a0.w[2]) : "v"(s0[2][0]), "v"(s0[2][1]));
            asm("v_cvt_pk_bf16_f32 %0, %1, %2" : "=v"(a0.w[3]) : "v"(s0[2][2]), "v"(s0[2][3]));
            asm("v_cvt_pk_bf16_f32 %0, %1, %2" : "=v"(a1.w[0]) : "v"(s0[1][0]), "v"(s0[1][1]));
            asm("v_cvt_pk_bf16_f32 %0, %1, %2" : "=v"(a1.w[1]) : "v"(s0[1][2]), "v"(s0[1][3]));
            asm("v_cvt_pk_bf16_f32 %0, %1, %2" : "=v"(a1.w[2]) : "v"(s0[3][0]), "v"(s0[3][1]));
            asm("v_cvt_pk_bf16_f32 %0, %1, %2" : "=v"(a1.w[3]) : "v"(s0[3][2]), "v"(s0[3][3]));
            asm("v_cvt_pk_bf16_f32 %0, %1, %2" : "=v"(b0.w[0]) : "v"(s1[0][0]), "v"(s1[0][1]));
            asm("v_cvt_pk_bf16_f32 %0, %1, %2" : "=v"(b0.w[1]) : "v"(s1[0][2]), "v"(s1[0][3]));
            asm("v_cvt_pk_bf16_f32 %0, %1, %2" : "=v"(b0.w[2]) : "v"(s1[2][0]), "v"(s1[2][1]));
            asm("v_cvt_pk_bf16_f32 %0, %1, %2" : "=v"(b0.w[3]) : "v"(s1[2][2]), "v"(s1[2][3]));
            asm("v_cvt_pk_bf16_f32 %0, %1, %2" : "=v"(b1.w[0]) : "v"(s1[1][0]), "v"(s1[1][1]));
            asm("v_cvt_pk_bf16_f32 %0, %1, %2" : "=v"(b1.w[1]) : "v"(s1[1][2]), "v"(s1[1][3]));
            asm("v_cvt_pk_bf16_f32 %0, %1, %2" : "=v"(b1.w[2]) : "v"(s1[3][0]), "v"(s1[3][1]));
            asm("v_cvt_pk_bf16_f32 %0, %1, %2" : "=v"(b1.w[3]) : "v"(s1[3][2]), "v"(s1[3][3]));
            bf16x8 pf0[2] = { a0.v, a1.v };
            bf16x8 pf1[2] = { b0.v, b1.v };

            // PV for both q-tiles, each V fragment read once; + l-sums
            __builtin_amdgcn_s_setprio(1);
            #pragma unroll
            for (int dt = 0; dt < 4; ++dt)
                #pragma unroll
                for (int kf = 0; kf < 2; ++kf) {
                    bf16x8 vfr = *(const bf16x8*)&Vts[foff[dt][kf]];
                    oacc0[dt] = __builtin_amdgcn_mfma_f32_16x16x32_bf16(pf0[kf], vfr, oacc0[dt], 0, 0, 0);
                    oacc1[dt] = __builtin_amdgcn_mfma_f32_16x16x32_bf16(pf1[kf], vfr, oacc1[dt], 0, 0, 0);
                }
            #pragma unroll
            for (int kf = 0; kf < 2; ++kf) {
                lacc0 = __builtin_amdgcn_mfma_f32_16x16x32_bf16(pf0[kf], ones, lacc0, 0, 0, 0);
                lacc1 = __builtin_amdgcn_mfma_f32_16x16x32_bf16(pf1[kf], ones, lacc1, 0, 0, 0);
            }
            __builtin_amdgcn_s_setprio(0);

            __syncthreads();   // drains my async loads; publishes tile kt+1
        }
    }

    // ---- in-block kv-merge (fixed-base softmax => partials add exactly) ----
    // Last loop barrier guarantees all LDS reads done -> safe to repurpose.
    float* mO = (float*)(&Kls[0][0][0]);   // 32 KB: [w4][qt][dt][lane] f32x4
    float* mL = (float*)(&Vls[0][0][0]);   // 8 KB:  [w4][qt][lane]     f32x4
    if (hk == 1) {
        #pragma unroll
        for (int dt = 0; dt < 4; ++dt) {
            *(f32x4*)&mO[(((w4*2 + 0)*4 + dt)*64 + lane)*4] = oacc0[dt];
            *(f32x4*)&mO[(((w4*2 + 1)*4 + dt)*64 + lane)*4] = oacc1[dt];
        }
        *(f32x4*)&mL[((w4*2 + 0)*64 + lane)*4] = lacc0;
        *(f32x4*)&mL[((w4*2 + 1)*64 + lane)*4] = lacc1;
    }
    __syncthreads();
    if (hk == 0) {
        #pragma unroll
        for (int dt = 0; dt < 4; ++dt) {
            oacc0[dt] += *(const f32x4*)&mO[(((w4*2 + 0)*4 + dt)*64 + lane)*4];
            oacc1[dt] += *(const f32x4*)&mO[(((w4*2 + 1)*4 + dt)*64 + lane)*4];
        }
        lacc0 += *(const f32x4*)&mL[((w4*2 + 0)*64 + lane)*4];
        lacc1 += *(const f32x4*)&mL[((w4*2 + 1)*64 + lane)*4];

        #pragma unroll
        for (int r = 0; r < 4; ++r) {
            float inv0 = 1.f / lacc0[r];
            float inv1 = 1.f / lacc1[r];
            size_t row0 = base + (size_t)(q0 + g4*4 + r)*64;
            size_t row1 = base + (size_t)(q0 + 16 + g4*4 + r)*64;
            #pragma unroll
            for (int dt = 0; dt < 4; ++dt) {
                ctx[row0 + dt*16 + ln] = f2bf(oacc0[dt][r] * inv0);
                ctx[row1 + dt*16 + ln] = f2bf(oacc1[dt][r] * inv1);
            }
        }
    }
}

// ---------------------------------------------------------------------------
// Kernel 3: MFMA output projection (flat-reshape A — round-4 lesson;
// async gload16 double-buffered staging — round-15 verified).
// ---------------------------------------------------------------------------
__global__ __launch_bounds__(256) void oproj_kernel(
    const u16* __restrict__ ctx, const u16* __restrict__ wob_t,
    const float* __restrict__ bo, float* __restrict__ out)
{
    __shared__ u16 Als[2][128*64];   // [buf][m][k], swizzled via source
    __shared__ u16 Bls[2][64*64];    // [buf][n][k], swizzled via source
    const int t = threadIdx.x;
    const int wid = t >> 6, lane = t & 63;
    const int ln = lane & 15, g4 = lane >> 4;
    const int wr = wid >> 1, wc = wid & 1;
    const int rb = blockIdx.x, cb = blockIdx.y;
    const int m0 = rb * 128;

    int gA[4], gB[2];
    #pragma unroll
    for (int c = 0; c < 4; ++c) {
        int slot = c*256 + t;
        int row = slot >> 3, ks = slot & 7;
        gA[c] = row*1024 + ((ks ^ (row & 7)) << 3);
    }
    #pragma unroll
    for (int c = 0; c < 2; ++c) {
        int slot = c*256 + t;
        int row = slot >> 3, ks = slot & 7;
        gB[c] = row*64 + ((ks ^ (row & 7)) << 3);
    }
    const u16* actx = ctx + (size_t)m0*1024;
    const u16* bw   = wob_t + (size_t)cb*16*4096;

    f32x4 acc[4][2];
    #pragma unroll
    for (int mf = 0; mf < 4; ++mf)
        #pragma unroll
        for (int nf = 0; nf < 2; ++nf)
            acc[mf][nf] = (f32x4){0.f, 0.f, 0.f, 0.f};

    #pragma unroll
    for (int c = 0; c < 4; ++c) gload16(&actx[gA[c]], &Als[0][(c*256+t)*8]);
    #pragma unroll
    for (int c = 0; c < 2; ++c) gload16(&bw[gB[c]],   &Bls[0][(c*256+t)*8]);
    __syncthreads();

    for (int kt2 = 0; kt2 < 8; ++kt2) {
        #pragma unroll
        for (int half = 0; half < 2; ++half) {
            const int kt = kt2*2 + half;
            if (kt < 15) {
                #pragma unroll
                for (int c = 0; c < 4; ++c)
                    gload16(&actx[(kt+1)*64 + gA[c]], &Als[half^1][(c*256+t)*8]);
                #pragma unroll
                for (int c = 0; c < 2; ++c)
                    gload16(&bw[(kt+1)*4096 + gB[c]], &Bls[half^1][(c*256+t)*8]);
            }
            const u16* As = Als[half];
            const u16* Bs = Bls[half];

            __builtin_amdgcn_s_setprio(1);
            #pragma unroll
            for (int kf = 0; kf < 2; ++kf) {
                bf16x8 af[4], bfr[2];
                #pragma unroll
                for (int mf = 0; mf < 4; ++mf) {
                    int arow = wr*64 + mf*16 + ln;
                    af[mf] = *(const bf16x8*)&As[arow*64 + (((kf*4 + g4) ^ (arow & 7)) << 3)];
                }
                #pragma unroll
                for (int nf = 0; nf < 2; ++nf) {
                    int brow = wc*32 + nf*16 + ln;
                    bfr[nf] = *(const bf16x8*)&Bs[brow*64 + (((kf*4 + g4) ^ (brow & 7)) << 3)];
                }
                #pragma unroll
                for (int mf = 0; mf < 4; ++mf)
                    #pragma unroll
                    for (int nf = 0; nf < 2; ++nf)
                        acc[mf][nf] = __builtin_amdgcn_mfma_f32_16x16x32_bf16(
                            af[mf], bfr[nf], acc[mf][nf], 0, 0, 0);
            }
            __builtin_amdgcn_s_setprio(0);

            __syncthreads();
        }
    }

    #pragma unroll
    for (int mf = 0; mf < 4; ++mf)
        #pragma unroll
        for (int r = 0; r < 4; ++r) {
            int m = m0 + wr*64 + mf*16 + g4*4 + r;
            #pragma unroll
            for (int nf = 0; nf < 2; ++nf) {
                int col = cb*64 + wc*32 + nf*16 + ln;
                out[(size_t)m*1024 + col] = acc[mf][nf][r] + bo[col];
            }
        }
}

extern "C" void kernel_launch(void* const* d_in, const int* in_sizes, int n_in,
                              void* d_out, int out_size, void* d_ws, size_t ws_size,
                              hipStream_t stream) {
    (void)in_sizes; (void)n_in; (void)out_size; (void)ws_size;
    const float* x  = (const float*)d_in[0];
    const float* wq = (const float*)d_in[1];
    const float* bq = (const float*)d_in[2];
    const float* wk = (const float*)d_in[3];
    const float* bk = (const float*)d_in[4];
    const float* wv = (const float*)d_in[5];
    const float* bv = (const float*)d_in[6];
    const float* wo = (const float*)d_in[7];
    const float* bo = (const float*)d_in[8];
    float* out = (float*)d_out;

    u16* Qb  = (u16*)d_ws;
    u16* Kb  = Qb + (size_t)NROWS*64;
    u16* Vgb = Kb + (size_t)NROWS*64;
    u16* ctx = Vgb + (size_t)NROWS*64;
    u16* wob_t = ctx + (size_t)NROWS*64;

    qkv_wconv_kernel<<<dim3(1024), 256, 0, stream>>>(
        x, wq, bq, wk, bk, wv, bv, wo, Qb, Kb, Vgb, wob_t);
    attn_kernel<<<dim3(16, 32), 512, 0, stream>>>(Qb, Kb, Vgb, ctx);
    oproj_kernel<<<dim3(32, 16), 256, 0, stream>>>(ctx, wob_t, bo, out);
}

// Round 20
// 67.840 us; speedup vs baseline: 1.1805x; 1.0333x over previous
//
#include <hip/hip_runtime.h>
#include <hip/hip_bf16.h>

#define SEQ 2048
#define BHCOUNT 32
#define NROWS (BHCOUNT*SEQ)   /* 65536 rows of [64] */

typedef unsigned short u16;
typedef unsigned int u32;
using bf16x8 = __attribute__((ext_vector_type(8))) short;   // 8 bf16 = 4 VGPR
using f32x4  = __attribute__((ext_vector_type(4))) float;

__device__ __forceinline__ float bf2f(u16 h) {
    return __uint_as_float(((u32)h) << 16);
}
__device__ __forceinline__ u16 f2bf(float f) {
    u32 u = __float_as_uint(f);
    u32 r = (u + 0x7FFFu + ((u >> 16) & 1u)) >> 16;
    return (u16)r;
}
// raw v_exp_f32 (2^x). Flushes tiny results to 0 — fine for softmax tails.
__device__ __forceinline__ float fexp2(float x) {
    float r; asm("v_exp_f32 %0, %1" : "=v"(r) : "v"(x)); return r;
}

// async global->LDS, 16B per lane. Global addr is PER-LANE, LDS dest is
// wave-uniform base + lane*16 (m104). Size must be a literal.
__device__ __forceinline__ void gload16(const u16* g, u16* l) {
    __builtin_amdgcn_global_load_lds(
        (const __attribute__((address_space(1))) u32*)g,
        (__attribute__((address_space(3))) u32*)l, 16, 0, 0);
}

__device__ __forceinline__ void cvt8(const float* src, float sc, u16* o) {
    float4 a = *(const float4*)src;
    float4 b = *(const float4*)(src + 4);
    o[0]=f2bf(a.x*sc); o[1]=f2bf(a.y*sc); o[2]=f2bf(a.z*sc); o[3]=f2bf(a.w*sc);
    o[4]=f2bf(b.x*sc); o[5]=f2bf(b.y*sc); o[6]=f2bf(b.z*sc); o[7]=f2bf(b.w*sc);
}

// ---------------------------------------------------------------------------
// Kernel 1: MFMA QKV projection (round-8 verified body) FUSED with wconv.
// Vg kappa order: the 16x16 mapping (rounds 5-17, verified):
//   kv = 16*nt + 4*g4 + r  <->  kappa = 32*(nt&1) + 8*g4 + 4*(nt>>1) + r
// ---------------------------------------------------------------------------
__global__ __launch_bounds__(256) void qkv_wconv_kernel(
    const float* __restrict__ x,
    const float* __restrict__ wq, const float* __restrict__ bq,
    const float* __restrict__ wk, const float* __restrict__ bk,
    const float* __restrict__ wv, const float* __restrict__ bv,
    const float* __restrict__ wo,
    u16* __restrict__ Q, u16* __restrict__ K, u16* __restrict__ Vg,
    u16* __restrict__ wob_t)
{
    __shared__ u16 xs[128*64];   // x tile bf16 swizzled; later vstage[64][128]
    __shared__ u16 ws[192*64];   // wq|wk|wv bf16, swizzled, qscale folded in wq
    __shared__ float bs[192];    // bq*qscale | bk | bv
    const int t = threadIdx.x;

    if (blockIdx.x >= 512) {     // ---- wconv part (block-uniform branch) ----
        int g = (blockIdx.x - 512)*256 + t;   // 131072 slots of 8 elems
        int tile = g >> 9, within = g & 511;
        int row = within >> 3, ks = within & 7;
        int cb = tile >> 4, kt = tile & 15;
        u16 o[8];
        cvt8(&wo[(size_t)(cb*64 + row)*1024 + kt*64 + ks*8], 1.f, o);
        *(uint4*)&wob_t[(size_t)g*8] = *(uint4*)o;
        return;
    }

    const int wid = t >> 6, lane = t & 63;
    const int ln = lane & 15, g4 = lane >> 4;
    const int blk = blockIdx.x;
    const int m0 = blk * 128;
    const int bh = blk >> 4;
    const int ktg0 = (blk & 15) * 2;
    const float qscale = 0.125f * 1.44269504f;

    #pragma unroll
    for (int c = 0; c < 6; ++c) {
        int slot = c*256 + t;
        int row = slot >> 3, ks = slot & 7;
        const float* wsrc = (c < 2) ? wq : (c < 4) ? wk : wv;
        float sc = (c < 2) ? qscale : 1.f;
        u16 o[8];
        cvt8(&wsrc[(row & 63)*64 + ks*8], sc, o);
        *(uint4*)&ws[row*64 + ((ks ^ (row & 7)) << 3)] = *(uint4*)o;
    }
    #pragma unroll
    for (int c = 0; c < 4; ++c) {
        int slot = c*256 + t;
        int row = slot >> 3, ks = slot & 7;
        u16 o[8];
        cvt8(&x[(size_t)(m0 + row)*64 + ks*8], 1.f, o);
        *(uint4*)&xs[row*64 + ((ks ^ (row & 7)) << 3)] = *(uint4*)o;
    }
    if (t < 192) {
        int p = t >> 6, e = t & 63;
        bs[t] = (p == 0) ? bq[e]*qscale : (p == 1) ? bk[e] : bv[e];
    }
    __syncthreads();

    bf16x8 af[2][2];
    #pragma unroll
    for (int mf = 0; mf < 2; ++mf)
        #pragma unroll
        for (int kf = 0; kf < 2; ++kf) {
            int arow = wid*32 + mf*16 + ln;
            af[mf][kf] = *(const bf16x8*)&xs[arow*64 + (((kf*4 + g4) ^ (arow & 7)) << 3)];
        }

    #pragma unroll
    for (int p = 0; p < 2; ++p) {
        bf16x8 bfr[4][2];
        #pragma unroll
        for (int nt = 0; nt < 4; ++nt)
            #pragma unroll
            for (int kf = 0; kf < 2; ++kf) {
                int brow = p*64 + nt*16 + ln;
                bfr[nt][kf] = *(const bf16x8*)&ws[brow*64 + (((kf*4 + g4) ^ (ln & 7)) << 3)];
            }
        f32x4 acc[2][4];
        #pragma unroll
        for (int mf = 0; mf < 2; ++mf)
            #pragma unroll
            for (int nt = 0; nt < 4; ++nt) acc[mf][nt] = (f32x4){0.f,0.f,0.f,0.f};
        #pragma unroll
        for (int kf = 0; kf < 2; ++kf)
            #pragma unroll
            for (int mf = 0; mf < 2; ++mf)
                #pragma unroll
                for (int nt = 0; nt < 4; ++nt)
                    acc[mf][nt] = __builtin_amdgcn_mfma_f32_16x16x32_bf16(
                        af[mf][kf], bfr[nt][kf], acc[mf][nt], 0, 0, 0);
        u16* dst = p ? K : Q;
        #pragma unroll
        for (int mf = 0; mf < 2; ++mf)
            #pragma unroll
            for (int nt = 0; nt < 4; ++nt) {
                float bv4 = bs[p*64 + nt*16 + ln];
                #pragma unroll
                for (int r = 0; r < 4; ++r)
                    dst[(size_t)(m0 + wid*32 + mf*16 + g4*4 + r)*64 + nt*16 + ln]
                        = f2bf(acc[mf][nt][r] + bv4);
            }
    }

    bf16x8 wvf[4][2];
    #pragma unroll
    for (int et = 0; et < 4; ++et)
        #pragma unroll
        for (int kf = 0; kf < 2; ++kf) {
            int brow = 128 + et*16 + ln;
            wvf[et][kf] = *(const bf16x8*)&ws[brow*64 + (((kf*4 + g4) ^ (ln & 7)) << 3)];
        }
    f32x4 vacc[4][2];
    #pragma unroll
    for (int et = 0; et < 4; ++et)
        #pragma unroll
        for (int st = 0; st < 2; ++st) vacc[et][st] = (f32x4){0.f,0.f,0.f,0.f};
    #pragma unroll
    for (int kf = 0; kf < 2; ++kf)
        #pragma unroll
        for (int et = 0; et < 4; ++et)
            #pragma unroll
            for (int st = 0; st < 2; ++st)
                vacc[et][st] = __builtin_amdgcn_mfma_f32_16x16x32_bf16(
                    wvf[et][kf], af[st][kf], vacc[et][st], 0, 0, 0);

    __syncthreads();
    u16* vstage = xs;
    #pragma unroll
    for (int et = 0; et < 4; ++et)
        #pragma unroll
        for (int st = 0; st < 2; ++st)
            #pragma unroll
            for (int r = 0; r < 4; ++r) {
                int e = et*16 + g4*4 + r;
                int s = wid*32 + st*16 + ln;
                vstage[e*128 + ((s + 2*e) & 127)] = f2bf(vacc[et][st][r] + bs[128 + e]);
            }
    __syncthreads();

    // write kappa-permuted tiles (16x16 order, rounds 5-17 verified)
    #pragma unroll
    for (int c = 0; c < 8; ++c) {
        int j = c*256 + t;
        int kt2 = j >> 10, within = j & 1023;
        int ee = within >> 4, kp0 = (within & 15) * 4;
        int sbase = ((kp0 & 4) << 3) | ((kp0 & 32) >> 1) | ((kp0 & 24) >> 1);
        u16 o[4];
        #pragma unroll
        for (int i = 0; i < 4; ++i)
            o[i] = vstage[ee*128 + ((kt2*64 + sbase + i + 2*ee) & 127)];
        *(uint2*)&Vg[((size_t)bh*32 + ktg0 + kt2)*4096 + ee*64 + kp0] = *(uint2*)o;
    }
}

// ---------------------------------------------------------------------------
// Kernel 2: MFMA flash attention, swapped-QK^T, 16x16 frags.
// Round 20: XCD-aware block remap (T1). r19 body byte-identical; only the
// (q-tile, bh) assignment changes. Linear dispatch id b = x + 16*y maps to
// XCD b%8 (round-robin). Remap:
//   xcd = b&7, j = b>>3, bh = xcd*4 + (j>>4), qtile = j&15   (bijective)
// -> all 16 q-blocks of a bh land on ONE XCD; 4 bh x 512KB K/V = 2MB < 4MB
// L2 -> after first touch all K/V tile prefetches are L2 hits (~200cyc vs
// ~900), and HBM FETCH drops ~70MB -> ~30MB (the diagnostic signature).
// ---------------------------------------------------------------------------
__global__ __launch_bounds__(512, 4) void attn_kernel(
    const u16* __restrict__ Q, const u16* __restrict__ K,
    const u16* __restrict__ Vg, u16* __restrict__ ctx)
{
    __shared__ u16 Kls[2][2][4096];   // [kvhalf][buf][tile]
    __shared__ u16 Vls[2][2][4096];

    const int t = threadIdx.x;          // 0..511
    const int wid = t >> 6, lane = t & 63;
    const int hk = wid >> 2;            // kv half: 0 or 1
    const int w4 = wid & 3;             // wave within half
    const int tt = t & 255;             // thread within half
    const int ln = lane & 15, g4 = lane >> 4;

    // XCD-aware remap (T1): all blocks of one bh on one XCD
    const int b = blockIdx.y * 16 + blockIdx.x;   // dispatch-linear id
    const int xcd = b & 7, j = b >> 3;
    const int bh = xcd * 4 + (j >> 4);
    const int qtile = j & 15;

    const size_t base   = (size_t)bh * SEQ * 64;
    const size_t vgbase = (size_t)bh * 32 * 4096;
    const int q0 = qtile * 128 + w4 * 32;
    const int kt0 = hk * 16;            // this half's first kv tile

    // staging: 512 slots of 16B per 64x64 tile, spread over this half's
    // 256 threads; thread tt stages slots tt and tt+256.
    int goff[2];
    #pragma unroll
    for (int c = 0; c < 2; ++c) {
        int s = c*256 + tt;
        int row = s >> 3, ks = s & 7;
        goff[c] = row*64 + ((ks ^ (row & 7)) << 3);
    }
    // LDS dest for chunk c: element c*2048 + w4*512 within [hk][buf]

    int foff[4][2];
    #pragma unroll
    for (int nt = 0; nt < 4; ++nt)
        #pragma unroll
        for (int kf = 0; kf < 2; ++kf) {
            int frow = nt*16 + ln;
            foff[nt][kf] = frow*64 + (((kf*4 + g4) ^ (frow & 7)) << 3);
        }

    // Q fragments for BOTH q-tiles (B-operand of swapped QK^T)
    bf16x8 qf0[2], qf1[2];
    #pragma unroll
    for (int kf = 0; kf < 2; ++kf) {
        qf0[kf] = *(const bf16x8*)&Q[base + (size_t)(q0 + ln)*64      + kf*32 + g4*8];
        qf1[kf] = *(const bf16x8*)&Q[base + (size_t)(q0 + 16 + ln)*64 + kf*32 + g4*8];
    }

    bf16x8 ones;
    #pragma unroll
    for (int i = 0; i < 8; ++i) ones[i] = (short)0x3F80;   // bf16 1.0

    f32x4 oacc0[4], oacc1[4];
    #pragma unroll
    for (int i = 0; i < 4; ++i) {
        oacc0[i] = (f32x4){0.f, 0.f, 0.f, 0.f};
        oacc1[i] = (f32x4){0.f, 0.f, 0.f, 0.f};
    }
    f32x4 lacc0 = (f32x4){0.f, 0.f, 0.f, 0.f};
    f32x4 lacc1 = (f32x4){0.f, 0.f, 0.f, 0.f};

    // prologue: stage this half's tile kt0 into buf 0
    #pragma unroll
    for (int c = 0; c < 2; ++c) {
        gload16(&K [base   + (size_t)kt0*4096 + goff[c]], &Kls[hk][0][c*2048 + w4*512]);
        gload16(&Vg[vgbase + (size_t)kt0*4096 + goff[c]], &Vls[hk][0][c*2048 + w4*512]);
    }
    __syncthreads();

    for (int kt2 = 0; kt2 < 8; ++kt2) {
        #pragma unroll
        for (int pb = 0; pb < 2; ++pb) {
            const int kt = kt2*2 + pb;
            if (kt < 15) {   // issue next tile's async loads into other buffer
                #pragma unroll
                for (int c = 0; c < 2; ++c) {
                    gload16(&K [base   + (size_t)(kt0+kt+1)*4096 + goff[c]],
                            &Kls[hk][pb^1][c*2048 + w4*512]);
                    gload16(&Vg[vgbase + (size_t)(kt0+kt+1)*4096 + goff[c]],
                            &Vls[hk][pb^1][c*2048 + w4*512]);
                }
            }
            const u16* Ks  = Kls[hk][pb];
            const u16* Vts = Vls[hk][pb];

            // QK^T for both q-tiles, each K fragment read once
            f32x4 s0[4], s1[4];
            #pragma unroll
            for (int nt = 0; nt < 4; ++nt) {
                s0[nt] = (f32x4){0.f, 0.f, 0.f, 0.f};
                s1[nt] = (f32x4){0.f, 0.f, 0.f, 0.f};
            }
            __builtin_amdgcn_s_setprio(1);
            #pragma unroll
            for (int nt = 0; nt < 4; ++nt)
                #pragma unroll
                for (int kf = 0; kf < 2; ++kf) {
                    bf16x8 kfr = *(const bf16x8*)&Ks[foff[nt][kf]];
                    s0[nt] = __builtin_amdgcn_mfma_f32_16x16x32_bf16(kfr, qf0[kf], s0[nt], 0, 0, 0);
                    s1[nt] = __builtin_amdgcn_mfma_f32_16x16x32_bf16(kfr, qf1[kf], s1[nt], 0, 0, 0);
                }
            __builtin_amdgcn_s_setprio(0);

            // softmax, fixed base m = 0 (r14-verified)
            #pragma unroll
            for (int nt = 0; nt < 4; ++nt)
                #pragma unroll
                for (int r = 0; r < 4; ++r) {
                    s0[nt][r] = fexp2(s0[nt][r]);
                    s1[nt][r] = fexp2(s1[nt][r]);
                }

            union PU { u32 w[4]; bf16x8 v; } a0, a1, b0, b1;
            asm("v_cvt_pk_bf16_f32 %0, %1, %2" : "=v"(a0.w[0]) : "v"(s0[0][0]), "v"(s0[0][1]));
            asm("v_cvt_pk_bf16_f32 %0, %1, %2" : "=v"(a0.w[1]) : "v"(s0[0][2]), "v"(s0[0][3]));
            asm("v_cvt_pk_bf16_f32 %0, %1, %2" : "=v"(a0.w[2]) : "v"(s0[2][0]), "v"(s0[2][1]));
            asm("v_cvt_pk_bf16_f32 %0, %1, %2" : "=v"(a0.w[3]) : "v"(s0[2][2]), "v"(s0[2][3]));
            asm("v_cvt_pk_bf16_f32 %0, %1, %2" : "=v"(a1.w[0]) : "v"(s0[1][0]), "v"(s0[1][1]));
            asm("v_cvt_pk_bf16_f32 %0, %1, %2" : "=v"(a1.w[1]) : "v"(s0[1][2]), "v"(s0[1][3]));
            asm("v_cvt_pk_bf16_f32 %0, %1, %2" : "=v"(a1.w[2]) : "v"(s0[3][0]), "v"(s0[3][1]));
            asm("v_cvt_pk_bf16_f32 %0, %1, %2" : "=v"(a1.w[3]) : "v"(s0[3][2]), "v"(s0[3][3]));
            asm("v_cvt_pk_bf16_f32 %0, %1, %2" : "=v"(b0.w[0]) : "v"(s1[0][0]), "v"(s1[0][1]));
            asm("v_cvt_pk_bf16_f32 %0, %1, %2" : "=v"(b0.w[1]) : "v"(s1[0][2]), "v"(s1[0][3]));
            asm("v_cvt_pk_bf16_f32 %0, %1, %2" : "=v"(b0.w[2]) : "v"(s1[2][0]), "v"(s1[2][1]));
            asm("v_cvt_pk_bf16_f32 %0, %1, %2" : "=v"(b0.w[3]) : "v"(s1[2][2]), "v"(s1[2][3]));
            asm("v_cvt_pk_bf16_f32 %0, %1, %2" : "=v"(b1.w[0]) : "v"(s1[1][0]), "v"(s1[1][1]));
            asm("v_cvt_pk_bf16_f32 %0, %1, %2" : "=v"(b1.w[1]) : "v"(s1[1][2]), "v"(s1[1][3]));
            asm("v_cvt_pk_bf16_f32 %0, %1, %2" : "=v"(b1.w[2]) : "v"(s1[3][0]), "v"(s1[3][1]));
            asm("v_cvt_pk_bf16_f32 %0, %1, %2" : "=v"(b1.w[3]) : "v"(s1[3][2]), "v"(s1[3][3]));
            bf16x8 pf0[2] = { a0.v, a1.v };
            bf16x8 pf1[2] = { b0.v, b1.v };

            // PV for both q-tiles, each V fragment read once; + l-sums
            __builtin_amdgcn_s_setprio(1);
            #pragma unroll
            for (int dt = 0; dt < 4; ++dt)
                #pragma unroll
                for (int kf = 0; kf < 2; ++kf) {
                    bf16x8 vfr = *(const bf16x8*)&Vts[foff[dt][kf]];
                    oacc0[dt] = __builtin_amdgcn_mfma_f32_16x16x32_bf16(pf0[kf], vfr, oacc0[dt], 0, 0, 0);
                    oacc1[dt] = __builtin_amdgcn_mfma_f32_16x16x32_bf16(pf1[kf], vfr, oacc1[dt], 0, 0, 0);
                }
            #pragma unroll
            for (int kf = 0; kf < 2; ++kf) {
                lacc0 = __builtin_amdgcn_mfma_f32_16x16x32_bf16(pf0[kf], ones, lacc0, 0, 0, 0);
                lacc1 = __builtin_amdgcn_mfma_f32_16x16x32_bf16(pf1[kf], ones, lacc1, 0, 0, 0);
            }
            __builtin_amdgcn_s_setprio(0);

            __syncthreads();   // drains my async loads; publishes tile kt+1
        }
    }

    // ---- in-block kv-merge (fixed-base softmax => partials add exactly) ----
    // Last loop barrier guarantees all LDS reads done -> safe to repurpose.
    float* mO = (float*)(&Kls[0][0][0]);   // 32 KB: [w4][qt][dt][lane] f32x4
    float* mL = (float*)(&Vls[0][0][0]);   // 8 KB:  [w4][qt][lane]     f32x4
    if (hk == 1) {
        #pragma unroll
        for (int dt = 0; dt < 4; ++dt) {
            *(f32x4*)&mO[(((w4*2 + 0)*4 + dt)*64 + lane)*4] = oacc0[dt];
            *(f32x4*)&mO[(((w4*2 + 1)*4 + dt)*64 + lane)*4] = oacc1[dt];
        }
        *(f32x4*)&mL[((w4*2 + 0)*64 + lane)*4] = lacc0;
        *(f32x4*)&mL[((w4*2 + 1)*64 + lane)*4] = lacc1;
    }
    __syncthreads();
    if (hk == 0) {
        #pragma unroll
        for (int dt = 0; dt < 4; ++dt) {
            oacc0[dt] += *(const f32x4*)&mO[(((w4*2 + 0)*4 + dt)*64 + lane)*4];
            oacc1[dt] += *(const f32x4*)&mO[(((w4*2 + 1)*4 + dt)*64 + lane)*4];
        }
        lacc0 += *(const f32x4*)&mL[((w4*2 + 0)*64 + lane)*4];
        lacc1 += *(const f32x4*)&mL[((w4*2 + 1)*64 + lane)*4];

        #pragma unroll
        for (int r = 0; r < 4; ++r) {
            float inv0 = 1.f / lacc0[r];
            float inv1 = 1.f / lacc1[r];
            size_t row0 = base + (size_t)(q0 + g4*4 + r)*64;
            size_t row1 = base + (size_t)(q0 + 16 + g4*4 + r)*64;
            #pragma unroll
            for (int dt = 0; dt < 4; ++dt) {
                ctx[row0 + dt*16 + ln] = f2bf(oacc0[dt][r] * inv0);
                ctx[row1 + dt*16 + ln] = f2bf(oacc1[dt][r] * inv1);
            }
        }
    }
}

// ---------------------------------------------------------------------------
// Kernel 3: MFMA output projection (flat-reshape A — round-4 lesson;
// async gload16 double-buffered staging — round-15 verified).
// ---------------------------------------------------------------------------
__global__ __launch_bounds__(256) void oproj_kernel(
    const u16* __restrict__ ctx, const u16* __restrict__ wob_t,
    const float* __restrict__ bo, float* __restrict__ out)
{
    __shared__ u16 Als[2][128*64];   // [buf][m][k], swizzled via source
    __shared__ u16 Bls[2][64*64];    // [buf][n][k], swizzled via source
    const int t = threadIdx.x;
    const int wid = t >> 6, lane = t & 63;
    const int ln = lane & 15, g4 = lane >> 4;
    const int wr = wid >> 1, wc = wid & 1;
    const int rb = blockIdx.x, cb = blockIdx.y;
    const int m0 = rb * 128;

    int gA[4], gB[2];
    #pragma unroll
    for (int c = 0; c < 4; ++c) {
        int slot = c*256 + t;
        int row = slot >> 3, ks = slot & 7;
        gA[c] = row*1024 + ((ks ^ (row & 7)) << 3);
    }
    #pragma unroll
    for (int c = 0; c < 2; ++c) {
        int slot = c*256 + t;
        int row = slot >> 3, ks = slot & 7;
        gB[c] = row*64 + ((ks ^ (row & 7)) << 3);
    }
    const u16* actx = ctx + (size_t)m0*1024;
    const u16* bw   = wob_t + (size_t)cb*16*4096;

    f32x4 acc[4][2];
    #pragma unroll
    for (int mf = 0; mf < 4; ++mf)
        #pragma unroll
        for (int nf = 0; nf < 2; ++nf)
            acc[mf][nf] = (f32x4){0.f, 0.f, 0.f, 0.f};

    #pragma unroll
    for (int c = 0; c < 4; ++c) gload16(&actx[gA[c]], &Als[0][(c*256+t)*8]);
    #pragma unroll
    for (int c = 0; c < 2; ++c) gload16(&bw[gB[c]],   &Bls[0][(c*256+t)*8]);
    __syncthreads();

    for (int kt2 = 0; kt2 < 8; ++kt2) {
        #pragma unroll
        for (int half = 0; half < 2; ++half) {
            const int kt = kt2*2 + half;
            if (kt < 15) {
                #pragma unroll
                for (int c = 0; c < 4; ++c)
                    gload16(&actx[(kt+1)*64 + gA[c]], &Als[half^1][(c*256+t)*8]);
                #pragma unroll
                for (int c = 0; c < 2; ++c)
                    gload16(&bw[(kt+1)*4096 + gB[c]], &Bls[half^1][(c*256+t)*8]);
            }
            const u16* As = Als[half];
            const u16* Bs = Bls[half];

            __builtin_amdgcn_s_setprio(1);
            #pragma unroll
            for (int kf = 0; kf < 2; ++kf) {
                bf16x8 af[4], bfr[2];
                #pragma unroll
                for (int mf = 0; mf < 4; ++mf) {
                    int arow = wr*64 + mf*16 + ln;
                    af[mf] = *(const bf16x8*)&As[arow*64 + (((kf*4 + g4) ^ (arow & 7)) << 3)];
                }
                #pragma unroll
                for (int nf = 0; nf < 2; ++nf) {
                    int brow = wc*32 + nf*16 + ln;
                    bfr[nf] = *(const bf16x8*)&Bs[brow*64 + (((kf*4 + g4) ^ (brow & 7)) << 3)];
                }
                #pragma unroll
                for (int mf = 0; mf < 4; ++mf)
                    #pragma unroll
                    for (int nf = 0; nf < 2; ++nf)
                        acc[mf][nf] = __builtin_amdgcn_mfma_f32_16x16x32_bf16(
                            af[mf], bfr[nf], acc[mf][nf], 0, 0, 0);
            }
            __builtin_amdgcn_s_setprio(0);

            __syncthreads();
        }
    }

    #pragma unroll
    for (int mf = 0; mf < 4; ++mf)
        #pragma unroll
        for (int r = 0; r < 4; ++r) {
            int m = m0 + wr*64 + mf*16 + g4*4 + r;
            #pragma unroll
            for (int nf = 0; nf < 2; ++nf) {
                int col = cb*64 + wc*32 + nf*16 + ln;
                out[(size_t)m*1024 + col] = acc[mf][nf][r] + bo[col];
            }
        }
}

extern "C" void kernel_launch(void* const* d_in, const int* in_sizes, int n_in,
                              void* d_out, int out_size, void* d_ws, size_t ws_size,
                              hipStream_t stream) {
    (void)in_sizes; (void)n_in; (void)out_size; (void)ws_size;
    const float* x  = (const float*)d_in[0];
    const float* wq = (const float*)d_in[1];
    const float* bq = (const float*)d_in[2];
    const float* wk = (const float*)d_in[3];
    const float* bk = (const float*)d_in[4];
    const float* wv = (const float*)d_in[5];
    const float* bv = (const float*)d_in[6];
    const float* wo = (const float*)d_in[7];
    const float* bo = (const float*)d_in[8];
    float* out = (float*)d_out;

    u16* Qb  = (u16*)d_ws;
    u16* Kb  = Qb + (size_t)NROWS*64;
    u16* Vgb = Kb + (size_t)NROWS*64;
    u16* ctx = Vgb + (size_t)NROWS*64;
    u16* wob_t = ctx + (size_t)NROWS*64;

    qkv_wconv_kernel<<<dim3(1024), 256, 0, stream>>>(
        x, wq, bq, wk, bk, wv, bv, wo, Qb, Kb, Vgb, wob_t);
    attn_kernel<<<dim3(16, 32), 512, 0, stream>>>(Qb, Kb, Vgb, ctx);
    oproj_kernel<<<dim3(32, 16), 256, 0, stream>>>(ctx, wob_t, bo, out);
}

// Round 21
// 67.574 us; speedup vs baseline: 1.1852x; 1.0039x over previous
//
#include <hip/hip_runtime.h>
#include <hip/hip_bf16.h>

#define SEQ 2048
#define BHCOUNT 32
#define NROWS (BHCOUNT*SEQ)   /* 65536 rows of [64] */

typedef unsigned short u16;
typedef unsigned int u32;
using bf16x8 = __attribute__((ext_vector_type(8))) short;   // 8 bf16 = 4 VGPR
using f32x4  = __attribute__((ext_vector_type(4))) float;

__device__ __forceinline__ float bf2f(u16 h) {
    return __uint_as_float(((u32)h) << 16);
}
__device__ __forceinline__ u16 f2bf(float f) {
    u32 u = __float_as_uint(f);
    u32 r = (u + 0x7FFFu + ((u >> 16) & 1u)) >> 16;
    return (u16)r;
}
// raw v_exp_f32 (2^x). Flushes tiny results to 0 — fine for softmax tails.
__device__ __forceinline__ float fexp2(float x) {
    float r; asm("v_exp_f32 %0, %1" : "=v"(r) : "v"(x)); return r;
}

// async global->LDS, 16B per lane. Global addr is PER-LANE, LDS dest is
// wave-uniform base + lane*16 (m104). Size must be a literal.
__device__ __forceinline__ void gload16(const u16* g, u16* l) {
    __builtin_amdgcn_global_load_lds(
        (const __attribute__((address_space(1))) u32*)g,
        (__attribute__((address_space(3))) u32*)l, 16, 0, 0);
}

__device__ __forceinline__ void cvt8(const float* src, float sc, u16* o) {
    float4 a = *(const float4*)src;
    float4 b = *(const float4*)(src + 4);
    o[0]=f2bf(a.x*sc); o[1]=f2bf(a.y*sc); o[2]=f2bf(a.z*sc); o[3]=f2bf(a.w*sc);
    o[4]=f2bf(b.x*sc); o[5]=f2bf(b.y*sc); o[6]=f2bf(b.z*sc); o[7]=f2bf(b.w*sc);
}

// ---------------------------------------------------------------------------
// Kernel 1: MFMA QKV projection (round-8 verified body) FUSED with wconv.
// Vg kappa order: the 16x16 mapping (rounds 5-17, verified):
//   kv = 16*nt + 4*g4 + r  <->  kappa = 32*(nt&1) + 8*g4 + 4*(nt>>1) + r
// ---------------------------------------------------------------------------
__global__ __launch_bounds__(256) void qkv_wconv_kernel(
    const float* __restrict__ x,
    const float* __restrict__ wq, const float* __restrict__ bq,
    const float* __restrict__ wk, const float* __restrict__ bk,
    const float* __restrict__ wv, const float* __restrict__ bv,
    const float* __restrict__ wo,
    u16* __restrict__ Q, u16* __restrict__ K, u16* __restrict__ Vg,
    u16* __restrict__ wob_t)
{
    __shared__ u16 xs[128*64];   // x tile bf16 swizzled; later vstage[64][128]
    __shared__ u16 ws[192*64];   // wq|wk|wv bf16, swizzled, qscale folded in wq
    __shared__ float bs[192];    // bq*qscale | bk | bv
    const int t = threadIdx.x;

    if (blockIdx.x >= 512) {     // ---- wconv part (block-uniform branch) ----
        int g = (blockIdx.x - 512)*256 + t;   // 131072 slots of 8 elems
        int tile = g >> 9, within = g & 511;
        int row = within >> 3, ks = within & 7;
        int cb = tile >> 4, kt = tile & 15;
        u16 o[8];
        cvt8(&wo[(size_t)(cb*64 + row)*1024 + kt*64 + ks*8], 1.f, o);
        *(uint4*)&wob_t[(size_t)g*8] = *(uint4*)o;
        return;
    }

    const int wid = t >> 6, lane = t & 63;
    const int ln = lane & 15, g4 = lane >> 4;
    const int blk = blockIdx.x;
    const int m0 = blk * 128;
    const int bh = blk >> 4;
    const int ktg0 = (blk & 15) * 2;
    const float qscale = 0.125f * 1.44269504f;

    #pragma unroll
    for (int c = 0; c < 6; ++c) {
        int slot = c*256 + t;
        int row = slot >> 3, ks = slot & 7;
        const float* wsrc = (c < 2) ? wq : (c < 4) ? wk : wv;
        float sc = (c < 2) ? qscale : 1.f;
        u16 o[8];
        cvt8(&wsrc[(row & 63)*64 + ks*8], sc, o);
        *(uint4*)&ws[row*64 + ((ks ^ (row & 7)) << 3)] = *(uint4*)o;
    }
    #pragma unroll
    for (int c = 0; c < 4; ++c) {
        int slot = c*256 + t;
        int row = slot >> 3, ks = slot & 7;
        u16 o[8];
        cvt8(&x[(size_t)(m0 + row)*64 + ks*8], 1.f, o);
        *(uint4*)&xs[row*64 + ((ks ^ (row & 7)) << 3)] = *(uint4*)o;
    }
    if (t < 192) {
        int p = t >> 6, e = t & 63;
        bs[t] = (p == 0) ? bq[e]*qscale : (p == 1) ? bk[e] : bv[e];
    }
    __syncthreads();

    bf16x8 af[2][2];
    #pragma unroll
    for (int mf = 0; mf < 2; ++mf)
        #pragma unroll
        for (int kf = 0; kf < 2; ++kf) {
            int arow = wid*32 + mf*16 + ln;
            af[mf][kf] = *(const bf16x8*)&xs[arow*64 + (((kf*4 + g4) ^ (arow & 7)) << 3)];
        }

    #pragma unroll
    for (int p = 0; p < 2; ++p) {
        bf16x8 bfr[4][2];
        #pragma unroll
        for (int nt = 0; nt < 4; ++nt)
            #pragma unroll
            for (int kf = 0; kf < 2; ++kf) {
                int brow = p*64 + nt*16 + ln;
                bfr[nt][kf] = *(const bf16x8*)&ws[brow*64 + (((kf*4 + g4) ^ (ln & 7)) << 3)];
            }
        f32x4 acc[2][4];
        #pragma unroll
        for (int mf = 0; mf < 2; ++mf)
            #pragma unroll
            for (int nt = 0; nt < 4; ++nt) acc[mf][nt] = (f32x4){0.f,0.f,0.f,0.f};
        #pragma unroll
        for (int kf = 0; kf < 2; ++kf)
            #pragma unroll
            for (int mf = 0; mf < 2; ++mf)
                #pragma unroll
                for (int nt = 0; nt < 4; ++nt)
                    acc[mf][nt] = __builtin_amdgcn_mfma_f32_16x16x32_bf16(
                        af[mf][kf], bfr[nt][kf], acc[mf][nt], 0, 0, 0);
        u16* dst = p ? K : Q;
        #pragma unroll
        for (int mf = 0; mf < 2; ++mf)
            #pragma unroll
            for (int nt = 0; nt < 4; ++nt) {
                float bv4 = bs[p*64 + nt*16 + ln];
                #pragma unroll
                for (int r = 0; r < 4; ++r)
                    dst[(size_t)(m0 + wid*32 + mf*16 + g4*4 + r)*64 + nt*16 + ln]
                        = f2bf(acc[mf][nt][r] + bv4);
            }
    }

    bf16x8 wvf[4][2];
    #pragma unroll
    for (int et = 0; et < 4; ++et)
        #pragma unroll
        for (int kf = 0; kf < 2; ++kf) {
            int brow = 128 + et*16 + ln;
            wvf[et][kf] = *(const bf16x8*)&ws[brow*64 + (((kf*4 + g4) ^ (ln & 7)) << 3)];
        }
    f32x4 vacc[4][2];
    #pragma unroll
    for (int et = 0; et < 4; ++et)
        #pragma unroll
        for (int st = 0; st < 2; ++st) vacc[et][st] = (f32x4){0.f,0.f,0.f,0.f};
    #pragma unroll
    for (int kf = 0; kf < 2; ++kf)
        #pragma unroll
        for (int et = 0; et < 4; ++et)
            #pragma unroll
            for (int st = 0; st < 2; ++st)
                vacc[et][st] = __builtin_amdgcn_mfma_f32_16x16x32_bf16(
                    wvf[et][kf], af[st][kf], vacc[et][st], 0, 0, 0);

    __syncthreads();
    u16* vstage = xs;
    #pragma unroll
    for (int et = 0; et < 4; ++et)
        #pragma unroll
        for (int st = 0; st < 2; ++st)
            #pragma unroll
            for (int r = 0; r < 4; ++r) {
                int e = et*16 + g4*4 + r;
                int s = wid*32 + st*16 + ln;
                vstage[e*128 + ((s + 2*e) & 127)] = f2bf(vacc[et][st][r] + bs[128 + e]);
            }
    __syncthreads();

    // write kappa-permuted tiles (16x16 order, rounds 5-17 verified)
    #pragma unroll
    for (int c = 0; c < 8; ++c) {
        int j = c*256 + t;
        int kt2 = j >> 10, within = j & 1023;
        int ee = within >> 4, kp0 = (within & 15) * 4;
        int sbase = ((kp0 & 4) << 3) | ((kp0 & 32) >> 1) | ((kp0 & 24) >> 1);
        u16 o[4];
        #pragma unroll
        for (int i = 0; i < 4; ++i)
            o[i] = vstage[ee*128 + ((kt2*64 + sbase + i + 2*ee) & 127)];
        *(uint2*)&Vg[((size_t)bh*32 + ktg0 + kt2)*4096 + ee*64 + kp0] = *(uint2*)o;
    }
}

// ---------------------------------------------------------------------------
// Kernel 2: MFMA flash attention, swapped-QK^T, 16x16 frags.
// Round 20: XCD-aware block remap (T1). r19 body byte-identical; only the
// (q-tile, bh) assignment changes. Linear dispatch id b = x + 16*y maps to
// XCD b%8 (round-robin). Remap:
//   xcd = b&7, j = b>>3, bh = xcd*4 + (j>>4), qtile = j&15   (bijective)
// -> all 16 q-blocks of a bh land on ONE XCD; 4 bh x 512KB K/V = 2MB < 4MB
// L2 -> after first touch all K/V tile prefetches are L2 hits (~200cyc vs
// ~900), and HBM FETCH drops ~70MB -> ~30MB (the diagnostic signature).
// ---------------------------------------------------------------------------
__global__ __launch_bounds__(512, 4) void attn_kernel(
    const u16* __restrict__ Q, const u16* __restrict__ K,
    const u16* __restrict__ Vg, u16* __restrict__ ctx)
{
    __shared__ u16 Kls[2][2][4096];   // [kvhalf][buf][tile]
    __shared__ u16 Vls[2][2][4096];

    const int t = threadIdx.x;          // 0..511
    const int wid = t >> 6, lane = t & 63;
    const int hk = wid >> 2;            // kv half: 0 or 1
    const int w4 = wid & 3;             // wave within half
    const int tt = t & 255;             // thread within half
    const int ln = lane & 15, g4 = lane >> 4;

    // XCD-aware remap (T1): all blocks of one bh on one XCD
    const int b = blockIdx.y * 16 + blockIdx.x;   // dispatch-linear id
    const int xcd = b & 7, j = b >> 3;
    const int bh = xcd * 4 + (j >> 4);
    const int qtile = j & 15;

    const size_t base   = (size_t)bh * SEQ * 64;
    const size_t vgbase = (size_t)bh * 32 * 4096;
    const int q0 = qtile * 128 + w4 * 32;
    const int kt0 = hk * 16;            // this half's first kv tile

    // staging: 512 slots of 16B per 64x64 tile, spread over this half's
    // 256 threads; thread tt stages slots tt and tt+256.
    int goff[2];
    #pragma unroll
    for (int c = 0; c < 2; ++c) {
        int s = c*256 + tt;
        int row = s >> 3, ks = s & 7;
        goff[c] = row*64 + ((ks ^ (row & 7)) << 3);
    }
    // LDS dest for chunk c: element c*2048 + w4*512 within [hk][buf]

    int foff[4][2];
    #pragma unroll
    for (int nt = 0; nt < 4; ++nt)
        #pragma unroll
        for (int kf = 0; kf < 2; ++kf) {
            int frow = nt*16 + ln;
            foff[nt][kf] = frow*64 + (((kf*4 + g4) ^ (frow & 7)) << 3);
        }

    // Q fragments for BOTH q-tiles (B-operand of swapped QK^T)
    bf16x8 qf0[2], qf1[2];
    #pragma unroll
    for (int kf = 0; kf < 2; ++kf) {
        qf0[kf] = *(const bf16x8*)&Q[base + (size_t)(q0 + ln)*64      + kf*32 + g4*8];
        qf1[kf] = *(const bf16x8*)&Q[base + (size_t)(q0 + 16 + ln)*64 + kf*32 + g4*8];
    }

    bf16x8 ones;
    #pragma unroll
    for (int i = 0; i < 8; ++i) ones[i] = (short)0x3F80;   // bf16 1.0

    f32x4 oacc0[4], oacc1[4];
    #pragma unroll
    for (int i = 0; i < 4; ++i) {
        oacc0[i] = (f32x4){0.f, 0.f, 0.f, 0.f};
        oacc1[i] = (f32x4){0.f, 0.f, 0.f, 0.f};
    }
    f32x4 lacc0 = (f32x4){0.f, 0.f, 0.f, 0.f};
    f32x4 lacc1 = (f32x4){0.f, 0.f, 0.f, 0.f};

    // prologue: stage this half's tile kt0 into buf 0
    #pragma unroll
    for (int c = 0; c < 2; ++c) {
        gload16(&K [base   + (size_t)kt0*4096 + goff[c]], &Kls[hk][0][c*2048 + w4*512]);
        gload16(&Vg[vgbase + (size_t)kt0*4096 + goff[c]], &Vls[hk][0][c*2048 + w4*512]);
    }
    __syncthreads();

    for (int kt2 = 0; kt2 < 8; ++kt2) {
        #pragma unroll
        for (int pb = 0; pb < 2; ++pb) {
            const int kt = kt2*2 + pb;
            if (kt < 15) {   // issue next tile's async loads into other buffer
                #pragma unroll
                for (int c = 0; c < 2; ++c) {
                    gload16(&K [base   + (size_t)(kt0+kt+1)*4096 + goff[c]],
                            &Kls[hk][pb^1][c*2048 + w4*512]);
                    gload16(&Vg[vgbase + (size_t)(kt0+kt+1)*4096 + goff[c]],
                            &Vls[hk][pb^1][c*2048 + w4*512]);
                }
            }
            const u16* Ks  = Kls[hk][pb];
            const u16* Vts = Vls[hk][pb];

            // QK^T for both q-tiles, each K fragment read once
            f32x4 s0[4], s1[4];
            #pragma unroll
            for (int nt = 0; nt < 4; ++nt) {
                s0[nt] = (f32x4){0.f, 0.f, 0.f, 0.f};
                s1[nt] = (f32x4){0.f, 0.f, 0.f, 0.f};
            }
            __builtin_amdgcn_s_setprio(1);
            #pragma unroll
            for (int nt = 0; nt < 4; ++nt)
                #pragma unroll
                for (int kf = 0; kf < 2; ++kf) {
                    bf16x8 kfr = *(const bf16x8*)&Ks[foff[nt][kf]];
                    s0[nt] = __builtin_amdgcn_mfma_f32_16x16x32_bf16(kfr, qf0[kf], s0[nt], 0, 0, 0);
                    s1[nt] = __builtin_amdgcn_mfma_f32_16x16x32_bf16(kfr, qf1[kf], s1[nt], 0, 0, 0);
                }
            __builtin_amdgcn_s_setprio(0);

            // softmax, fixed base m = 0 (r14-verified)
            #pragma unroll
            for (int nt = 0; nt < 4; ++nt)
                #pragma unroll
                for (int r = 0; r < 4; ++r) {
                    s0[nt][r] = fexp2(s0[nt][r]);
                    s1[nt][r] = fexp2(s1[nt][r]);
                }

            union PU { u32 w[4]; bf16x8 v; } a0, a1, b0, b1;
            asm("v_cvt_pk_bf16_f32 %0, %1, %2" : "=v"(a0.w[0]) : "v"(s0[0][0]), "v"(s0[0][1]));
            asm("v_cvt_pk_bf16_f32 %0, %1, %2" : "=v"(a0.w[1]) : "v"(s0[0][2]), "v"(s0[0][3]));
            asm("v_cvt_pk_bf16_f32 %0, %1, %2" : "=v"(a0.w[2]) : "v"(s0[2][0]), "v"(s0[2][1]));
            asm("v_cvt_pk_bf16_f32 %0, %1, %2" : "=v"(a0.w[3]) : "v"(s0[2][2]), "v"(s0[2][3]));
            asm("v_cvt_pk_bf16_f32 %0, %1, %2" : "=v"(a1.w[0]) : "v"(s0[1][0]), "v"(s0[1][1]));
            asm("v_cvt_pk_bf16_f32 %0, %1, %2" : "=v"(a1.w[1]) : "v"(s0[1][2]), "v"(s0[1][3]));
            asm("v_cvt_pk_bf16_f32 %0, %1, %2" : "=v"(a1.w[2]) : "v"(s0[3][0]), "v"(s0[3][1]));
            asm("v_cvt_pk_bf16_f32 %0, %1, %2" : "=v"(a1.w[3]) : "v"(s0[3][2]), "v"(s0[3][3]));
            asm("v_cvt_pk_bf16_f32 %0, %1, %2" : "=v"(b0.w[0]) : "v"(s1[0][0]), "v"(s1[0][1]));
            asm("v_cvt_pk_bf16_f32 %0, %1, %2" : "=v"(b0.w[1]) : "v"(s1[0][2]), "v"(s1[0][3]));
            asm("v_cvt_pk_bf16_f32 %0, %1, %2" : "=v"(b0.w[2]) : "v"(s1[2][0]), "v"(s1[2][1]));
            asm("v_cvt_pk_bf16_f32 %0, %1, %2" : "=v"(b0.w[3]) : "v"(s1[2][2]), "v"(s1[2][3]));
            asm("v_cvt_pk_bf16_f32 %0, %1, %2" : "=v"(b1.w[0]) : "v"(s1[1][0]), "v"(s1[1][1]));
            asm("v_cvt_pk_bf16_f32 %0, %1, %2" : "=v"(b1.w[1]) : "v"(s1[1][2]), "v"(s1[1][3]));
            asm("v_cvt_pk_bf16_f32 %0, %1, %2" : "=v"(b1.w[2]) : "v"(s1[3][0]), "v"(s1[3][1]));
            asm("v_cvt_pk_bf16_f32 %0, %1, %2" : "=v"(b1.w[3]) : "v"(s1[3][2]), "v"(s1[3][3]));
            bf16x8 pf0[2] = { a0.v, a1.v };
            bf16x8 pf1[2] = { b0.v, b1.v };

            // PV for both q-tiles, each V fragment read once; + l-sums
            __builtin_amdgcn_s_setprio(1);
            #pragma unroll
            for (int dt = 0; dt < 4; ++dt)
                #pragma unroll
                for (int kf = 0; kf < 2; ++kf) {
                    bf16x8 vfr = *(const bf16x8*)&Vts[foff[dt][kf]];
                    oacc0[dt] = __builtin_amdgcn_mfma_f32_16x16x32_bf16(pf0[kf], vfr, oacc0[dt], 0, 0, 0);
                    oacc1[dt] = __builtin_amdgcn_mfma_f32_16x16x32_bf16(pf1[kf], vfr, oacc1[dt], 0, 0, 0);
                }
            #pragma unroll
            for (int kf = 0; kf < 2; ++kf) {
                lacc0 = __builtin_amdgcn_mfma_f32_16x16x32_bf16(pf0[kf], ones, lacc0, 0, 0, 0);
                lacc1 = __builtin_amdgcn_mfma_f32_16x16x32_bf16(pf1[kf], ones, lacc1, 0, 0, 0);
            }
            __builtin_amdgcn_s_setprio(0);

            __syncthreads();   // drains my async loads; publishes tile kt+1
        }
    }

    // ---- in-block kv-merge (fixed-base softmax => partials add exactly) ----
    // Last loop barrier guarantees all LDS reads done -> safe to repurpose.
    float* mO = (float*)(&Kls[0][0][0]);   // 32 KB: [w4][qt][dt][lane] f32x4
    float* mL = (float*)(&Vls[0][0][0]);   // 8 KB:  [w4][qt][lane]     f32x4
    if (hk == 1) {
        #pragma unroll
        for (int dt = 0; dt < 4; ++dt) {
            *(f32x4*)&mO[(((w4*2 + 0)*4 + dt)*64 + lane)*4] = oacc0[dt];
            *(f32x4*)&mO[(((w4*2 + 1)*4 + dt)*64 + lane)*4] = oacc1[dt];
        }
        *(f32x4*)&mL[((w4*2 + 0)*64 + lane)*4] = lacc0;
        *(f32x4*)&mL[((w4*2 + 1)*64 + lane)*4] = lacc1;
    }
    __syncthreads();
    if (hk == 0) {
        #pragma unroll
        for (int dt = 0; dt < 4; ++dt) {
            oacc0[dt] += *(const f32x4*)&mO[(((w4*2 + 0)*4 + dt)*64 + lane)*4];
            oacc1[dt] += *(const f32x4*)&mO[(((w4*2 + 1)*4 + dt)*64 + lane)*4];
        }
        lacc0 += *(const f32x4*)&mL[((w4*2 + 0)*64 + lane)*4];
        lacc1 += *(const f32x4*)&mL[((w4*2 + 1)*64 + lane)*4];

        #pragma unroll
        for (int r = 0; r < 4; ++r) {
            float inv0 = 1.f / lacc0[r];
            float inv1 = 1.f / lacc1[r];
            size_t row0 = base + (size_t)(q0 + g4*4 + r)*64;
            size_t row1 = base + (size_t)(q0 + 16 + g4*4 + r)*64;
            #pragma unroll
            for (int dt = 0; dt < 4; ++dt) {
                ctx[row0 + dt*16 + ln] = f2bf(oacc0[dt][r] * inv0);
                ctx[row1 + dt*16 + ln] = f2bf(oacc1[dt][r] * inv1);
            }
        }
    }
}

// ---------------------------------------------------------------------------
// Kernel 3: MFMA output projection (flat-reshape A — round-4 lesson;
// async gload16 double-buffered staging — round-15 verified).
// ---------------------------------------------------------------------------
__global__ __launch_bounds__(256) void oproj_kernel(
    const u16* __restrict__ ctx, const u16* __restrict__ wob_t,
    const float* __restrict__ bo, float* __restrict__ out)
{
    __shared__ u16 Als[2][128*64];   // [buf][m][k], swizzled via source
    __shared__ u16 Bls[2][64*64];    // [buf][n][k], swizzled via source
    const int t = threadIdx.x;
    const int wid = t >> 6, lane = t & 63;
    const int ln = lane & 15, g4 = lane >> 4;
    const int wr = wid >> 1, wc = wid & 1;
    const int rb = blockIdx.x, cb = blockIdx.y;
    const int m0 = rb * 128;

    int gA[4], gB[2];
    #pragma unroll
    for (int c = 0; c < 4; ++c) {
        int slot = c*256 + t;
        int row = slot >> 3, ks = slot & 7;
        gA[c] = row*1024 + ((ks ^ (row & 7)) << 3);
    }
    #pragma unroll
    for (int c = 0; c < 2; ++c) {
        int slot = c*256 + t;
        int row = slot >> 3, ks = slot & 7;
        gB[c] = row*64 + ((ks ^ (row & 7)) << 3);
    }
    const u16* actx = ctx + (size_t)m0*1024;
    const u16* bw   = wob_t + (size_t)cb*16*4096;

    f32x4 acc[4][2];
    #pragma unroll
    for (int mf = 0; mf < 4; ++mf)
        #pragma unroll
        for (int nf = 0; nf < 2; ++nf)
            acc[mf][nf] = (f32x4){0.f, 0.f, 0.f, 0.f};

    #pragma unroll
    for (int c = 0; c < 4; ++c) gload16(&actx[gA[c]], &Als[0][(c*256+t)*8]);
    #pragma unroll
    for (int c = 0; c < 2; ++c) gload16(&bw[gB[c]],   &Bls[0][(c*256+t)*8]);
    __syncthreads();

    for (int kt2 = 0; kt2 < 8; ++kt2) {
        #pragma unroll
        for (int half = 0; half < 2; ++half) {
            const int kt = kt2*2 + half;
            if (kt < 15) {
                #pragma unroll
                for (int c = 0; c < 4; ++c)
                    gload16(&actx[(kt+1)*64 + gA[c]], &Als[half^1][(c*256+t)*8]);
                #pragma unroll
                for (int c = 0; c < 2; ++c)
                    gload16(&bw[(kt+1)*4096 + gB[c]], &Bls[half^1][(c*256+t)*8]);
            }
            const u16* As = Als[half];
            const u16* Bs = Bls[half];

            __builtin_amdgcn_s_setprio(1);
            #pragma unroll
            for (int kf = 0; kf < 2; ++kf) {
                bf16x8 af[4], bfr[2];
                #pragma unroll
                for (int mf = 0; mf < 4; ++mf) {
                    int arow = wr*64 + mf*16 + ln;
                    af[mf] = *(const bf16x8*)&As[arow*64 + (((kf*4 + g4) ^ (arow & 7)) << 3)];
                }
                #pragma unroll
                for (int nf = 0; nf < 2; ++nf) {
                    int brow = wc*32 + nf*16 + ln;
                    bfr[nf] = *(const bf16x8*)&Bs[brow*64 + (((kf*4 + g4) ^ (brow & 7)) << 3)];
                }
                #pragma unroll
                for (int mf = 0; mf < 4; ++mf)
                    #pragma unroll
                    for (int nf = 0; nf < 2; ++nf)
                        acc[mf][nf] = __builtin_amdgcn_mfma_f32_16x16x32_bf16(
                            af[mf], bfr[nf], acc[mf][nf], 0, 0, 0);
            }
            __builtin_amdgcn_s_setprio(0);

            __syncthreads();
        }
    }

    #pragma unroll
    for (int mf = 0; mf < 4; ++mf)
        #pragma unroll
        for (int r = 0; r < 4; ++r) {
            int m = m0 + wr*64 + mf*16 + g4*4 + r;
            #pragma unroll
            for (int nf = 0; nf < 2; ++nf) {
                int col = cb*64 + wc*32 + nf*16 + ln;
                out[(size_t)m*1024 + col] = acc[mf][nf][r] + bo[col];
            }
        }
}

extern "C" void kernel_launch(void* const* d_in, const int* in_sizes, int n_in,
                              void* d_out, int out_size, void* d_ws, size_t ws_size,
                              hipStream_t stream) {
    (void)in_sizes; (void)n_in; (void)out_size; (void)ws_size;
    const float* x  = (const float*)d_in[0];
    const float* wq = (const float*)d_in[1];
    const float* bq = (const float*)d_in[2];
    const float* wk = (const float*)d_in[3];
    const float* bk = (const float*)d_in[4];
    const float* wv = (const float*)d_in[5];
    const float* bv = (const float*)d_in[6];
    const float* wo = (const float*)d_in[7];
    const float* bo = (const float*)d_in[8];
    float* out = (float*)d_out;

    u16* Qb  = (u16*)d_ws;
    u16* Kb  = Qb + (size_t)NROWS*64;
    u16* Vgb = Kb + (size_t)NROWS*64;
    u16* ctx = Vgb + (size_t)NROWS*64;
    u16* wob_t = ctx + (size_t)NROWS*64;

    qkv_wconv_kernel<<<dim3(1024), 256, 0, stream>>>(
        x, wq, bq, wk, bk, wv, bv, wo, Qb, Kb, Vgb, wob_t);
    attn_kernel<<<dim3(16, 32), 512, 0, stream>>>(Qb, Kb, Vgb, ctx);
    oproj_kernel<<<dim3(32, 16), 256, 0, stream>>>(ctx, wob_t, bo, out);
}

// Round 22
// 67.472 us; speedup vs baseline: 1.1869x; 1.0015x over previous
//
#include <hip/hip_runtime.h>
#include <hip/hip_bf16.h>

#define SEQ 2048
#define BHCOUNT 32
#define NROWS (BHCOUNT*SEQ)   /* 65536 rows of [64] */

typedef unsigned short u16;
typedef unsigned int u32;
using bf16x8 = __attribute__((ext_vector_type(8))) short;   // 8 bf16 = 4 VGPR
using f32x4  = __attribute__((ext_vector_type(4))) float;

__device__ __forceinline__ float bf2f(u16 h) {
    return __uint_as_float(((u32)h) << 16);
}
// HW RNE fp32->bf16 (1 inst vs 4 VALU software round; same rounding => bit-identical)
__device__ __forceinline__ u16 f2bf(float f) {
    u32 r; asm("v_cvt_pk_bf16_f32 %0, %1, %1" : "=v"(r) : "v"(f));
    return (u16)r;
}
// raw v_exp_f32 (2^x). Flushes tiny results to 0 — fine for softmax tails.
__device__ __forceinline__ float fexp2(float x) {
    float r; asm("v_exp_f32 %0, %1" : "=v"(r) : "v"(x)); return r;
}

// async global->LDS, 16B per lane. Global addr is PER-LANE, LDS dest is
// wave-uniform base + lane*16 (m104). Size must be a literal.
__device__ __forceinline__ void gload16(const u16* g, u16* l) {
    __builtin_amdgcn_global_load_lds(
        (const __attribute__((address_space(1))) u32*)g,
        (__attribute__((address_space(3))) u32*)l, 16, 0, 0);
}

// fp32x8 -> bf16x8 via 4 packed converts (RNE, hardware)
__device__ __forceinline__ void cvt8(const float* src, float sc, u16* o) {
    float4 a = *(const float4*)src;
    float4 b = *(const float4*)(src + 4);
    u32* w = (u32*)o;
    asm("v_cvt_pk_bf16_f32 %0, %1, %2" : "=v"(w[0]) : "v"(a.x*sc), "v"(a.y*sc));
    asm("v_cvt_pk_bf16_f32 %0, %1, %2" : "=v"(w[1]) : "v"(a.z*sc), "v"(a.w*sc));
    asm("v_cvt_pk_bf16_f32 %0, %1, %2" : "=v"(w[2]) : "v"(b.x*sc), "v"(b.y*sc));
    asm("v_cvt_pk_bf16_f32 %0, %1, %2" : "=v"(w[3]) : "v"(b.z*sc), "v"(b.w*sc));
}

// ---------------------------------------------------------------------------
// Kernel 1: MFMA QKV projection (round-8 verified body) FUSED with wconv.
// Vg kappa order: the 16x16 mapping (rounds 5-17, verified):
//   kv = 16*nt + 4*g4 + r  <->  kappa = 32*(nt&1) + 8*g4 + 4*(nt>>1) + r
// ---------------------------------------------------------------------------
__global__ __launch_bounds__(256) void qkv_wconv_kernel(
    const float* __restrict__ x,
    const float* __restrict__ wq, const float* __restrict__ bq,
    const float* __restrict__ wk, const float* __restrict__ bk,
    const float* __restrict__ wv, const float* __restrict__ bv,
    const float* __restrict__ wo,
    u16* __restrict__ Q, u16* __restrict__ K, u16* __restrict__ Vg,
    u16* __restrict__ wob_t)
{
    __shared__ u16 xs[128*64];   // x tile bf16 swizzled; later vstage[64][128]
    __shared__ u16 ws[192*64];   // wq|wk|wv bf16, swizzled, qscale folded in wq
    __shared__ float bs[192];    // bq*qscale | bk | bv
    const int t = threadIdx.x;

    if (blockIdx.x >= 512) {     // ---- wconv part (block-uniform branch) ----
        int g = (blockIdx.x - 512)*256 + t;   // 131072 slots of 8 elems
        int tile = g >> 9, within = g & 511;
        int row = within >> 3, ks = within & 7;
        int cb = tile >> 4, kt = tile & 15;
        u16 o[8];
        cvt8(&wo[(size_t)(cb*64 + row)*1024 + kt*64 + ks*8], 1.f, o);
        *(uint4*)&wob_t[(size_t)g*8] = *(uint4*)o;
        return;
    }

    const int wid = t >> 6, lane = t & 63;
    const int ln = lane & 15, g4 = lane >> 4;
    const int blk = blockIdx.x;
    const int m0 = blk * 128;
    const int bh = blk >> 4;
    const int ktg0 = (blk & 15) * 2;
    const float qscale = 0.125f * 1.44269504f;

    #pragma unroll
    for (int c = 0; c < 6; ++c) {
        int slot = c*256 + t;
        int row = slot >> 3, ks = slot & 7;
        const float* wsrc = (c < 2) ? wq : (c < 4) ? wk : wv;
        float sc = (c < 2) ? qscale : 1.f;
        u16 o[8];
        cvt8(&wsrc[(row & 63)*64 + ks*8], sc, o);
        *(uint4*)&ws[row*64 + ((ks ^ (row & 7)) << 3)] = *(uint4*)o;
    }
    #pragma unroll
    for (int c = 0; c < 4; ++c) {
        int slot = c*256 + t;
        int row = slot >> 3, ks = slot & 7;
        u16 o[8];
        cvt8(&x[(size_t)(m0 + row)*64 + ks*8], 1.f, o);
        *(uint4*)&xs[row*64 + ((ks ^ (row & 7)) << 3)] = *(uint4*)o;
    }
    if (t < 192) {
        int p = t >> 6, e = t & 63;
        bs[t] = (p == 0) ? bq[e]*qscale : (p == 1) ? bk[e] : bv[e];
    }
    __syncthreads();

    bf16x8 af[2][2];
    #pragma unroll
    for (int mf = 0; mf < 2; ++mf)
        #pragma unroll
        for (int kf = 0; kf < 2; ++kf) {
            int arow = wid*32 + mf*16 + ln;
            af[mf][kf] = *(const bf16x8*)&xs[arow*64 + (((kf*4 + g4) ^ (arow & 7)) << 3)];
        }

    #pragma unroll
    for (int p = 0; p < 2; ++p) {
        bf16x8 bfr[4][2];
        #pragma unroll
        for (int nt = 0; nt < 4; ++nt)
            #pragma unroll
            for (int kf = 0; kf < 2; ++kf) {
                int brow = p*64 + nt*16 + ln;
                bfr[nt][kf] = *(const bf16x8*)&ws[brow*64 + (((kf*4 + g4) ^ (ln & 7)) << 3)];
            }
        f32x4 acc[2][4];
        #pragma unroll
        for (int mf = 0; mf < 2; ++mf)
            #pragma unroll
            for (int nt = 0; nt < 4; ++nt) acc[mf][nt] = (f32x4){0.f,0.f,0.f,0.f};
        #pragma unroll
        for (int kf = 0; kf < 2; ++kf)
            #pragma unroll
            for (int mf = 0; mf < 2; ++mf)
                #pragma unroll
                for (int nt = 0; nt < 4; ++nt)
                    acc[mf][nt] = __builtin_amdgcn_mfma_f32_16x16x32_bf16(
                        af[mf][kf], bfr[nt][kf], acc[mf][nt], 0, 0, 0);
        u16* dst = p ? K : Q;
        #pragma unroll
        for (int mf = 0; mf < 2; ++mf)
            #pragma unroll
            for (int nt = 0; nt < 4; ++nt) {
                float bv4 = bs[p*64 + nt*16 + ln];
                #pragma unroll
                for (int r = 0; r < 4; ++r)
                    dst[(size_t)(m0 + wid*32 + mf*16 + g4*4 + r)*64 + nt*16 + ln]
                        = f2bf(acc[mf][nt][r] + bv4);
            }
    }

    bf16x8 wvf[4][2];
    #pragma unroll
    for (int et = 0; et < 4; ++et)
        #pragma unroll
        for (int kf = 0; kf < 2; ++kf) {
            int brow = 128 + et*16 + ln;
            wvf[et][kf] = *(const bf16x8*)&ws[brow*64 + (((kf*4 + g4) ^ (ln & 7)) << 3)];
        }
    f32x4 vacc[4][2];
    #pragma unroll
    for (int et = 0; et < 4; ++et)
        #pragma unroll
        for (int st = 0; st < 2; ++st) vacc[et][st] = (f32x4){0.f,0.f,0.f,0.f};
    #pragma unroll
    for (int kf = 0; kf < 2; ++kf)
        #pragma unroll
        for (int et = 0; et < 4; ++et)
            #pragma unroll
            for (int st = 0; st < 2; ++st)
                vacc[et][st] = __builtin_amdgcn_mfma_f32_16x16x32_bf16(
                    wvf[et][kf], af[st][kf], vacc[et][st], 0, 0, 0);

    __syncthreads();
    u16* vstage = xs;
    #pragma unroll
    for (int et = 0; et < 4; ++et)
        #pragma unroll
        for (int st = 0; st < 2; ++st)
            #pragma unroll
            for (int r = 0; r < 4; ++r) {
                int e = et*16 + g4*4 + r;
                int s = wid*32 + st*16 + ln;
                vstage[e*128 + ((s + 2*e) & 127)] = f2bf(vacc[et][st][r] + bs[128 + e]);
            }
    __syncthreads();

    // write kappa-permuted tiles (16x16 order, rounds 5-17 verified)
    #pragma unroll
    for (int c = 0; c < 8; ++c) {
        int j = c*256 + t;
        int kt2 = j >> 10, within = j & 1023;
        int ee = within >> 4, kp0 = (within & 15) * 4;
        int sbase = ((kp0 & 4) << 3) | ((kp0 & 32) >> 1) | ((kp0 & 24) >> 1);
        u16 o[4];
        #pragma unroll
        for (int i = 0; i < 4; ++i)
            o[i] = vstage[ee*128 + ((kt2*64 + sbase + i + 2*ee) & 127)];
        *(uint2*)&Vg[((size_t)bh*32 + ktg0 + kt2)*4096 + ee*64 + kp0] = *(uint2*)o;
    }
}

// ---------------------------------------------------------------------------
// Kernel 2: MFMA flash attention, swapped-QK^T, 16x16 frags.
// XCD-aware remap (T1, round-21 verified: all 16 q-blocks of a bh on one
// XCD -> K/V L2-resident) + kv-split x q-reuse (r19) + fixed-base softmax
// (r14) + MFMA ones-column l-sum (r13). Body byte-identical to round 21.
// ---------------------------------------------------------------------------
__global__ __launch_bounds__(512, 4) void attn_kernel(
    const u16* __restrict__ Q, const u16* __restrict__ K,
    const u16* __restrict__ Vg, u16* __restrict__ ctx)
{
    __shared__ u16 Kls[2][2][4096];   // [kvhalf][buf][tile]
    __shared__ u16 Vls[2][2][4096];

    const int t = threadIdx.x;          // 0..511
    const int wid = t >> 6, lane = t & 63;
    const int hk = wid >> 2;            // kv half: 0 or 1
    const int w4 = wid & 3;             // wave within half
    const int tt = t & 255;             // thread within half
    const int ln = lane & 15, g4 = lane >> 4;

    // XCD-aware remap (T1): all blocks of one bh on one XCD
    const int b = blockIdx.y * 16 + blockIdx.x;   // dispatch-linear id
    const int xcd = b & 7, j = b >> 3;
    const int bh = xcd * 4 + (j >> 4);
    const int qtile = j & 15;

    const size_t base   = (size_t)bh * SEQ * 64;
    const size_t vgbase = (size_t)bh * 32 * 4096;
    const int q0 = qtile * 128 + w4 * 32;
    const int kt0 = hk * 16;            // this half's first kv tile

    // staging: 512 slots of 16B per 64x64 tile, spread over this half's
    // 256 threads; thread tt stages slots tt and tt+256.
    int goff[2];
    #pragma unroll
    for (int c = 0; c < 2; ++c) {
        int s = c*256 + tt;
        int row = s >> 3, ks = s & 7;
        goff[c] = row*64 + ((ks ^ (row & 7)) << 3);
    }
    // LDS dest for chunk c: element c*2048 + w4*512 within [hk][buf]

    int foff[4][2];
    #pragma unroll
    for (int nt = 0; nt < 4; ++nt)
        #pragma unroll
        for (int kf = 0; kf < 2; ++kf) {
            int frow = nt*16 + ln;
            foff[nt][kf] = frow*64 + (((kf*4 + g4) ^ (frow & 7)) << 3);
        }

    // Q fragments for BOTH q-tiles (B-operand of swapped QK^T)
    bf16x8 qf0[2], qf1[2];
    #pragma unroll
    for (int kf = 0; kf < 2; ++kf) {
        qf0[kf] = *(const bf16x8*)&Q[base + (size_t)(q0 + ln)*64      + kf*32 + g4*8];
        qf1[kf] = *(const bf16x8*)&Q[base + (size_t)(q0 + 16 + ln)*64 + kf*32 + g4*8];
    }

    bf16x8 ones;
    #pragma unroll
    for (int i = 0; i < 8; ++i) ones[i] = (short)0x3F80;   // bf16 1.0

    f32x4 oacc0[4], oacc1[4];
    #pragma unroll
    for (int i = 0; i < 4; ++i) {
        oacc0[i] = (f32x4){0.f, 0.f, 0.f, 0.f};
        oacc1[i] = (f32x4){0.f, 0.f, 0.f, 0.f};
    }
    f32x4 lacc0 = (f32x4){0.f, 0.f, 0.f, 0.f};
    f32x4 lacc1 = (f32x4){0.f, 0.f, 0.f, 0.f};

    // prologue: stage this half's tile kt0 into buf 0
    #pragma unroll
    for (int c = 0; c < 2; ++c) {
        gload16(&K [base   + (size_t)kt0*4096 + goff[c]], &Kls[hk][0][c*2048 + w4*512]);
        gload16(&Vg[vgbase + (size_t)kt0*4096 + goff[c]], &Vls[hk][0][c*2048 + w4*512]);
    }
    __syncthreads();

    for (int kt2 = 0; kt2 < 8; ++kt2) {
        #pragma unroll
        for (int pb = 0; pb < 2; ++pb) {
            const int kt = kt2*2 + pb;
            if (kt < 15) {   // issue next tile's async loads into other buffer
                #pragma unroll
                for (int c = 0; c < 2; ++c) {
                    gload16(&K [base   + (size_t)(kt0+kt+1)*4096 + goff[c]],
                            &Kls[hk][pb^1][c*2048 + w4*512]);
                    gload16(&Vg[vgbase + (size_t)(kt0+kt+1)*4096 + goff[c]],
                            &Vls[hk][pb^1][c*2048 + w4*512]);
                }
            }
            const u16* Ks  = Kls[hk][pb];
            const u16* Vts = Vls[hk][pb];

            // QK^T for both q-tiles, each K fragment read once
            f32x4 s0[4], s1[4];
            #pragma unroll
            for (int nt = 0; nt < 4; ++nt) {
                s0[nt] = (f32x4){0.f, 0.f, 0.f, 0.f};
                s1[nt] = (f32x4){0.f, 0.f, 0.f, 0.f};
            }
            __builtin_amdgcn_s_setprio(1);
            #pragma unroll
            for (int nt = 0; nt < 4; ++nt)
                #pragma unroll
                for (int kf = 0; kf < 2; ++kf) {
                    bf16x8 kfr = *(const bf16x8*)&Ks[foff[nt][kf]];
                    s0[nt] = __builtin_amdgcn_mfma_f32_16x16x32_bf16(kfr, qf0[kf], s0[nt], 0, 0, 0);
                    s1[nt] = __builtin_amdgcn_mfma_f32_16x16x32_bf16(kfr, qf1[kf], s1[nt], 0, 0, 0);
                }
            __builtin_amdgcn_s_setprio(0);

            // softmax, fixed base m = 0 (r14-verified)
            #pragma unroll
            for (int nt = 0; nt < 4; ++nt)
                #pragma unroll
                for (int r = 0; r < 4; ++r) {
                    s0[nt][r] = fexp2(s0[nt][r]);
                    s1[nt][r] = fexp2(s1[nt][r]);
                }

            union PU { u32 w[4]; bf16x8 v; } a0, a1, b0, b1;
            asm("v_cvt_pk_bf16_f32 %0, %1, %2" : "=v"(a0.w[0]) : "v"(s0[0][0]), "v"(s0[0][1]));
            asm("v_cvt_pk_bf16_f32 %0, %1, %2" : "=v"(a0.w[1]) : "v"(s0[0][2]), "v"(s0[0][3]));
            asm("v_cvt_pk_bf16_f32 %0, %1, %2" : "=v"(a0.w[2]) : "v"(s0[2][0]), "v"(s0[2][1]));
            asm("v_cvt_pk_bf16_f32 %0, %1, %2" : "=v"(a0.w[3]) : "v"(s0[2][2]), "v"(s0[2][3]));
            asm("v_cvt_pk_bf16_f32 %0, %1, %2" : "=v"(a1.w[0]) : "v"(s0[1][0]), "v"(s0[1][1]));
            asm("v_cvt_pk_bf16_f32 %0, %1, %2" : "=v"(a1.w[1]) : "v"(s0[1][2]), "v"(s0[1][3]));
            asm("v_cvt_pk_bf16_f32 %0, %1, %2" : "=v"(a1.w[2]) : "v"(s0[3][0]), "v"(s0[3][1]));
            asm("v_cvt_pk_bf16_f32 %0, %1, %2" : "=v"(a1.w[3]) : "v"(s0[3][2]), "v"(s0[3][3]));
            asm("v_cvt_pk_bf16_f32 %0, %1, %2" : "=v"(b0.w[0]) : "v"(s1[0][0]), "v"(s1[0][1]));
            asm("v_cvt_pk_bf16_f32 %0, %1, %2" : "=v"(b0.w[1]) : "v"(s1[0][2]), "v"(s1[0][3]));
            asm("v_cvt_pk_bf16_f32 %0, %1, %2" : "=v"(b0.w[2]) : "v"(s1[2][0]), "v"(s1[2][1]));
            asm("v_cvt_pk_bf16_f32 %0, %1, %2" : "=v"(b0.w[3]) : "v"(s1[2][2]), "v"(s1[2][3]));
            asm("v_cvt_pk_bf16_f32 %0, %1, %2" : "=v"(b1.w[0]) : "v"(s1[1][0]), "v"(s1[1][1]));
            asm("v_cvt_pk_bf16_f32 %0, %1, %2" : "=v"(b1.w[1]) : "v"(s1[1][2]), "v"(s1[1][3]));
            asm("v_cvt_pk_bf16_f32 %0, %1, %2" : "=v"(b1.w[2]) : "v"(s1[3][0]), "v"(s1[3][1]));
            asm("v_cvt_pk_bf16_f32 %0, %1, %2" : "=v"(b1.w[3]) : "v"(s1[3][2]), "v"(s1[3][3]));
            bf16x8 pf0[2] = { a0.v, a1.v };
            bf16x8 pf1[2] = { b0.v, b1.v };

            // PV for both q-tiles, each V fragment read once; + l-sums
            __builtin_amdgcn_s_setprio(1);
            #pragma unroll
            for (int dt = 0; dt < 4; ++dt)
                #pragma unroll
                for (int kf = 0; kf < 2; ++kf) {
                    bf16x8 vfr = *(const bf16x8*)&Vts[foff[dt][kf]];
                    oacc0[dt] = __builtin_amdgcn_mfma_f32_16x16x32_bf16(pf0[kf], vfr, oacc0[dt], 0, 0, 0);
                    oacc1[dt] = __builtin_amdgcn_mfma_f32_16x16x32_bf16(pf1[kf], vfr, oacc1[dt], 0, 0, 0);
                }
            #pragma unroll
            for (int kf = 0; kf < 2; ++kf) {
                lacc0 = __builtin_amdgcn_mfma_f32_16x16x32_bf16(pf0[kf], ones, lacc0, 0, 0, 0);
                lacc1 = __builtin_amdgcn_mfma_f32_16x16x32_bf16(pf1[kf], ones, lacc1, 0, 0, 0);
            }
            __builtin_amdgcn_s_setprio(0);

            __syncthreads();   // drains my async loads; publishes tile kt+1
        }
    }

    // ---- in-block kv-merge (fixed-base softmax => partials add exactly) ----
    // Last loop barrier guarantees all LDS reads done -> safe to repurpose.
    float* mO = (float*)(&Kls[0][0][0]);   // 32 KB: [w4][qt][dt][lane] f32x4
    float* mL = (float*)(&Vls[0][0][0]);   // 8 KB:  [w4][qt][lane]     f32x4
    if (hk == 1) {
        #pragma unroll
        for (int dt = 0; dt < 4; ++dt) {
            *(f32x4*)&mO[(((w4*2 + 0)*4 + dt)*64 + lane)*4] = oacc0[dt];
            *(f32x4*)&mO[(((w4*2 + 1)*4 + dt)*64 + lane)*4] = oacc1[dt];
        }
        *(f32x4*)&mL[((w4*2 + 0)*64 + lane)*4] = lacc0;
        *(f32x4*)&mL[((w4*2 + 1)*64 + lane)*4] = lacc1;
    }
    __syncthreads();
    if (hk == 0) {
        #pragma unroll
        for (int dt = 0; dt < 4; ++dt) {
            oacc0[dt] += *(const f32x4*)&mO[(((w4*2 + 0)*4 + dt)*64 + lane)*4];
            oacc1[dt] += *(const f32x4*)&mO[(((w4*2 + 1)*4 + dt)*64 + lane)*4];
        }
        lacc0 += *(const f32x4*)&mL[((w4*2 + 0)*64 + lane)*4];
        lacc1 += *(const f32x4*)&mL[((w4*2 + 1)*64 + lane)*4];

        #pragma unroll
        for (int r = 0; r < 4; ++r) {
            float inv0 = 1.f / lacc0[r];
            float inv1 = 1.f / lacc1[r];
            size_t row0 = base + (size_t)(q0 + g4*4 + r)*64;
            size_t row1 = base + (size_t)(q0 + 16 + g4*4 + r)*64;
            #pragma unroll
            for (int dt = 0; dt < 4; ++dt) {
                ctx[row0 + dt*16 + ln] = f2bf(oacc0[dt][r] * inv0);
                ctx[row1 + dt*16 + ln] = f2bf(oacc1[dt][r] * inv1);
            }
        }
    }
}

// ---------------------------------------------------------------------------
// Kernel 3: MFMA output projection (flat-reshape A — round-4 lesson;
// async gload16 double-buffered staging — round-15 verified).
// ---------------------------------------------------------------------------
__global__ __launch_bounds__(256) void oproj_kernel(
    const u16* __restrict__ ctx, const u16* __restrict__ wob_t,
    const float* __restrict__ bo, float* __restrict__ out)
{
    __shared__ u16 Als[2][128*64];   // [buf][m][k], swizzled via source
    __shared__ u16 Bls[2][64*64];    // [buf][n][k], swizzled via source
    const int t = threadIdx.x;
    const int wid = t >> 6, lane = t & 63;
    const int ln = lane & 15, g4 = lane >> 4;
    const int wr = wid >> 1, wc = wid & 1;
    const int rb = blockIdx.x, cb = blockIdx.y;
    const int m0 = rb * 128;

    int gA[4], gB[2];
    #pragma unroll
    for (int c = 0; c < 4; ++c) {
        int slot = c*256 + t;
        int row = slot >> 3, ks = slot & 7;
        gA[c] = row*1024 + ((ks ^ (row & 7)) << 3);
    }
    #pragma unroll
    for (int c = 0; c < 2; ++c) {
        int slot = c*256 + t;
        int row = slot >> 3, ks = slot & 7;
        gB[c] = row*64 + ((ks ^ (row & 7)) << 3);
    }
    const u16* actx = ctx + (size_t)m0*1024;
    const u16* bw   = wob_t + (size_t)cb*16*4096;

    f32x4 acc[4][2];
    #pragma unroll
    for (int mf = 0; mf < 4; ++mf)
        #pragma unroll
        for (int nf = 0; nf < 2; ++nf)
            acc[mf][nf] = (f32x4){0.f, 0.f, 0.f, 0.f};

    #pragma unroll
    for (int c = 0; c < 4; ++c) gload16(&actx[gA[c]], &Als[0][(c*256+t)*8]);
    #pragma unroll
    for (int c = 0; c < 2; ++c) gload16(&bw[gB[c]],   &Bls[0][(c*256+t)*8]);
    __syncthreads();

    for (int kt2 = 0; kt2 < 8; ++kt2) {
        #pragma unroll
        for (int half = 0; half < 2; ++half) {
            const int kt = kt2*2 + half;
            if (kt < 15) {
                #pragma unroll
                for (int c = 0; c < 4; ++c)
                    gload16(&actx[(kt+1)*64 + gA[c]], &Als[half^1][(c*256+t)*8]);
                #pragma unroll
                for (int c = 0; c < 2; ++c)
                    gload16(&bw[(kt+1)*4096 + gB[c]], &Bls[half^1][(c*256+t)*8]);
            }
            const u16* As = Als[half];
            const u16* Bs = Bls[half];

            __builtin_amdgcn_s_setprio(1);
            #pragma unroll
            for (int kf = 0; kf < 2; ++kf) {
                bf16x8 af[4], bfr[2];
                #pragma unroll
                for (int mf = 0; mf < 4; ++mf) {
                    int arow = wr*64 + mf*16 + ln;
                    af[mf] = *(const bf16x8*)&As[arow*64 + (((kf*4 + g4) ^ (arow & 7)) << 3)];
                }
                #pragma unroll
                for (int nf = 0; nf < 2; ++nf) {
                    int brow = wc*32 + nf*16 + ln;
                    bfr[nf] = *(const bf16x8*)&Bs[brow*64 + (((kf*4 + g4) ^ (brow & 7)) << 3)];
                }
                #pragma unroll
                for (int mf = 0; mf < 4; ++mf)
                    #pragma unroll
                    for (int nf = 0; nf < 2; ++nf)
                        acc[mf][nf] = __builtin_amdgcn_mfma_f32_16x16x32_bf16(
                            af[mf], bfr[nf], acc[mf][nf], 0, 0, 0);
            }
            __builtin_amdgcn_s_setprio(0);

            __syncthreads();
        }
    }

    #pragma unroll
    for (int mf = 0; mf < 4; ++mf)
        #pragma unroll
        for (int r = 0; r < 4; ++r) {
            int m = m0 + wr*64 + mf*16 + g4*4 + r;
            #pragma unroll
            for (int nf = 0; nf < 2; ++nf) {
                int col = cb*64 + wc*32 + nf*16 + ln;
                out[(size_t)m*1024 + col] = acc[mf][nf][r] + bo[col];
            }
        }
}

extern "C" void kernel_launch(void* const* d_in, const int* in_sizes, int n_in,
                              void* d_out, int out_size, void* d_ws, size_t ws_size,
                              hipStream_t stream) {
    (void)in_sizes; (void)n_in; (void)out_size; (void)ws_size;
    const float* x  = (const float*)d_in[0];
    const float* wq = (const float*)d_in[1];
    const float* bq = (const float*)d_in[2];
    const float* wk = (const float*)d_in[3];
    const float* bk = (const float*)d_in[4];
    const float* wv = (const float*)d_in[5];
    const float* bv = (const float*)d_in[6];
    const float* wo = (const float*)d_in[7];
    const float* bo = (const float*)d_in[8];
    float* out = (float*)d_out;

    u16* Qb  = (u16*)d_ws;
    u16* Kb  = Qb + (size_t)NROWS*64;
    u16* Vgb = Kb + (size_t)NROWS*64;
    u16* ctx = Vgb + (size_t)NROWS*64;
    u16* wob_t = ctx + (size_t)NROWS*64;

    qkv_wconv_kernel<<<dim3(1024), 256, 0, stream>>>(
        x, wq, bq, wk, bk, wv, bv, wo, Qb, Kb, Vgb, wob_t);
    attn_kernel<<<dim3(16, 32), 512, 0, stream>>>(Qb, Kb, Vgb, ctx);
    oproj_kernel<<<dim3(32, 16), 256, 0, stream>>>(ctx, wob_t, bo, out);
}

// Round 23
// 65.575 us; speedup vs baseline: 1.2213x; 1.0289x over previous
//
#include <hip/hip_runtime.h>
#include <hip/hip_bf16.h>

#define SEQ 2048
#define BHCOUNT 32
#define NROWS (BHCOUNT*SEQ)   /* 65536 rows of [64] */

typedef unsigned short u16;
typedef unsigned int u32;
using bf16x8 = __attribute__((ext_vector_type(8))) short;   // 8 bf16 = 4 VGPR
using f32x4  = __attribute__((ext_vector_type(4))) float;

__device__ __forceinline__ float bf2f(u16 h) {
    return __uint_as_float(((u32)h) << 16);
}
// HW RNE fp32->bf16 (1 inst; same rounding as software RNE => bit-identical)
__device__ __forceinline__ u16 f2bf(float f) {
    u32 r; asm("v_cvt_pk_bf16_f32 %0, %1, %1" : "=v"(r) : "v"(f));
    return (u16)r;
}
// raw v_exp_f32 (2^x). Flushes tiny results to 0 — fine for softmax tails.
__device__ __forceinline__ float fexp2(float x) {
    float r; asm("v_exp_f32 %0, %1" : "=v"(r) : "v"(x)); return r;
}

// async global->LDS, 16B per lane. Global addr is PER-LANE, LDS dest is
// wave-uniform base + lane*16 (m104). Size must be a literal.
__device__ __forceinline__ void gload16(const u16* g, u16* l) {
    __builtin_amdgcn_global_load_lds(
        (const __attribute__((address_space(1))) u32*)g,
        (__attribute__((address_space(3))) u32*)l, 16, 0, 0);
}

// fp32x8 -> bf16x8 via 4 packed converts (RNE, hardware)
__device__ __forceinline__ void cvt8(const float* src, float sc, u16* o) {
    float4 a = *(const float4*)src;
    float4 b = *(const float4*)(src + 4);
    u32* w = (u32*)o;
    asm("v_cvt_pk_bf16_f32 %0, %1, %2" : "=v"(w[0]) : "v"(a.x*sc), "v"(a.y*sc));
    asm("v_cvt_pk_bf16_f32 %0, %1, %2" : "=v"(w[1]) : "v"(a.z*sc), "v"(a.w*sc));
    asm("v_cvt_pk_bf16_f32 %0, %1, %2" : "=v"(w[2]) : "v"(b.x*sc), "v"(b.y*sc));
    asm("v_cvt_pk_bf16_f32 %0, %1, %2" : "=v"(w[3]) : "v"(b.z*sc), "v"(b.w*sc));
}

// ---------------------------------------------------------------------------
// Kernel 1: MFMA QKV projection (round-8 verified body) FUSED with wconv.
// Vg kappa order: the 16x16 mapping (rounds 5-17, verified):
//   kv = 16*nt + 4*g4 + r  <->  kappa = 32*(nt&1) + 8*g4 + 4*(nt>>1) + r
// ---------------------------------------------------------------------------
__global__ __launch_bounds__(256) void qkv_wconv_kernel(
    const float* __restrict__ x,
    const float* __restrict__ wq, const float* __restrict__ bq,
    const float* __restrict__ wk, const float* __restrict__ bk,
    const float* __restrict__ wv, const float* __restrict__ bv,
    const float* __restrict__ wo,
    u16* __restrict__ Q, u16* __restrict__ K, u16* __restrict__ Vg,
    u16* __restrict__ wob_t)
{
    __shared__ u16 xs[128*64];   // x tile bf16 swizzled; later vstage[64][128]
    __shared__ u16 ws[192*64];   // wq|wk|wv bf16, swizzled, qscale folded in wq
    __shared__ float bs[192];    // bq*qscale | bk | bv
    const int t = threadIdx.x;

    if (blockIdx.x >= 512) {     // ---- wconv part (block-uniform branch) ----
        int g = (blockIdx.x - 512)*256 + t;   // 131072 slots of 8 elems
        int tile = g >> 9, within = g & 511;
        int row = within >> 3, ks = within & 7;
        int cb = tile >> 4, kt = tile & 15;
        u16 o[8];
        cvt8(&wo[(size_t)(cb*64 + row)*1024 + kt*64 + ks*8], 1.f, o);
        *(uint4*)&wob_t[(size_t)g*8] = *(uint4*)o;
        return;
    }

    const int wid = t >> 6, lane = t & 63;
    const int ln = lane & 15, g4 = lane >> 4;
    const int blk = blockIdx.x;
    const int m0 = blk * 128;
    const int bh = blk >> 4;
    const int ktg0 = (blk & 15) * 2;
    const float qscale = 0.125f * 1.44269504f;

    #pragma unroll
    for (int c = 0; c < 6; ++c) {
        int slot = c*256 + t;
        int row = slot >> 3, ks = slot & 7;
        const float* wsrc = (c < 2) ? wq : (c < 4) ? wk : wv;
        float sc = (c < 2) ? qscale : 1.f;
        u16 o[8];
        cvt8(&wsrc[(row & 63)*64 + ks*8], sc, o);
        *(uint4*)&ws[row*64 + ((ks ^ (row & 7)) << 3)] = *(uint4*)o;
    }
    #pragma unroll
    for (int c = 0; c < 4; ++c) {
        int slot = c*256 + t;
        int row = slot >> 3, ks = slot & 7;
        u16 o[8];
        cvt8(&x[(size_t)(m0 + row)*64 + ks*8], 1.f, o);
        *(uint4*)&xs[row*64 + ((ks ^ (row & 7)) << 3)] = *(uint4*)o;
    }
    if (t < 192) {
        int p = t >> 6, e = t & 63;
        bs[t] = (p == 0) ? bq[e]*qscale : (p == 1) ? bk[e] : bv[e];
    }
    __syncthreads();

    bf16x8 af[2][2];
    #pragma unroll
    for (int mf = 0; mf < 2; ++mf)
        #pragma unroll
        for (int kf = 0; kf < 2; ++kf) {
            int arow = wid*32 + mf*16 + ln;
            af[mf][kf] = *(const bf16x8*)&xs[arow*64 + (((kf*4 + g4) ^ (arow & 7)) << 3)];
        }

    #pragma unroll
    for (int p = 0; p < 2; ++p) {
        bf16x8 bfr[4][2];
        #pragma unroll
        for (int nt = 0; nt < 4; ++nt)
            #pragma unroll
            for (int kf = 0; kf < 2; ++kf) {
                int brow = p*64 + nt*16 + ln;
                bfr[nt][kf] = *(const bf16x8*)&ws[brow*64 + (((kf*4 + g4) ^ (ln & 7)) << 3)];
            }
        f32x4 acc[2][4];
        #pragma unroll
        for (int mf = 0; mf < 2; ++mf)
            #pragma unroll
            for (int nt = 0; nt < 4; ++nt) acc[mf][nt] = (f32x4){0.f,0.f,0.f,0.f};
        #pragma unroll
        for (int kf = 0; kf < 2; ++kf)
            #pragma unroll
            for (int mf = 0; mf < 2; ++mf)
                #pragma unroll
                for (int nt = 0; nt < 4; ++nt)
                    acc[mf][nt] = __builtin_amdgcn_mfma_f32_16x16x32_bf16(
                        af[mf][kf], bfr[nt][kf], acc[mf][nt], 0, 0, 0);
        u16* dst = p ? K : Q;
        #pragma unroll
        for (int mf = 0; mf < 2; ++mf)
            #pragma unroll
            for (int nt = 0; nt < 4; ++nt) {
                float bv4 = bs[p*64 + nt*16 + ln];
                #pragma unroll
                for (int r = 0; r < 4; ++r)
                    dst[(size_t)(m0 + wid*32 + mf*16 + g4*4 + r)*64 + nt*16 + ln]
                        = f2bf(acc[mf][nt][r] + bv4);
            }
    }

    bf16x8 wvf[4][2];
    #pragma unroll
    for (int et = 0; et < 4; ++et)
        #pragma unroll
        for (int kf = 0; kf < 2; ++kf) {
            int brow = 128 + et*16 + ln;
            wvf[et][kf] = *(const bf16x8*)&ws[brow*64 + (((kf*4 + g4) ^ (ln & 7)) << 3)];
        }
    f32x4 vacc[4][2];
    #pragma unroll
    for (int et = 0; et < 4; ++et)
        #pragma unroll
        for (int st = 0; st < 2; ++st) vacc[et][st] = (f32x4){0.f,0.f,0.f,0.f};
    #pragma unroll
    for (int kf = 0; kf < 2; ++kf)
        #pragma unroll
        for (int et = 0; et < 4; ++et)
            #pragma unroll
            for (int st = 0; st < 2; ++st)
                vacc[et][st] = __builtin_amdgcn_mfma_f32_16x16x32_bf16(
                    wvf[et][kf], af[st][kf], vacc[et][st], 0, 0, 0);

    __syncthreads();
    u16* vstage = xs;
    #pragma unroll
    for (int et = 0; et < 4; ++et)
        #pragma unroll
        for (int st = 0; st < 2; ++st)
            #pragma unroll
            for (int r = 0; r < 4; ++r) {
                int e = et*16 + g4*4 + r;
                int s = wid*32 + st*16 + ln;
                vstage[e*128 + ((s + 2*e) & 127)] = f2bf(vacc[et][st][r] + bs[128 + e]);
            }
    __syncthreads();

    // write kappa-permuted tiles (16x16 order, rounds 5-17 verified)
    #pragma unroll
    for (int c = 0; c < 8; ++c) {
        int j = c*256 + t;
        int kt2 = j >> 10, within = j & 1023;
        int ee = within >> 4, kp0 = (within & 15) * 4;
        int sbase = ((kp0 & 4) << 3) | ((kp0 & 32) >> 1) | ((kp0 & 24) >> 1);
        u16 o[4];
        #pragma unroll
        for (int i = 0; i < 4; ++i)
            o[i] = vstage[ee*128 + ((kt2*64 + sbase + i + 2*ee) & 127)];
        *(uint2*)&Vg[((size_t)bh*32 + ktg0 + kt2)*4096 + ee*64 + kp0] = *(uint2*)o;
    }
}

// ---------------------------------------------------------------------------
// Kernel 2: MFMA flash attention, swapped-QK^T, 16x16 frags.
// XCD-aware remap (T1, round-21 verified) + kv-split x q-reuse (r19) +
// fixed-base softmax (r14) + MFMA ones-column l-sum (r13).
// Body byte-identical to rounds 21-22 (verified, ~40 us).
// ---------------------------------------------------------------------------
__global__ __launch_bounds__(512, 4) void attn_kernel(
    const u16* __restrict__ Q, const u16* __restrict__ K,
    const u16* __restrict__ Vg, u16* __restrict__ ctx)
{
    __shared__ u16 Kls[2][2][4096];   // [kvhalf][buf][tile]
    __shared__ u16 Vls[2][2][4096];

    const int t = threadIdx.x;          // 0..511
    const int wid = t >> 6, lane = t & 63;
    const int hk = wid >> 2;            // kv half: 0 or 1
    const int w4 = wid & 3;             // wave within half
    const int tt = t & 255;             // thread within half
    const int ln = lane & 15, g4 = lane >> 4;

    // XCD-aware remap (T1): all blocks of one bh on one XCD
    const int b = blockIdx.y * 16 + blockIdx.x;   // dispatch-linear id
    const int xcd = b & 7, j = b >> 3;
    const int bh = xcd * 4 + (j >> 4);
    const int qtile = j & 15;

    const size_t base   = (size_t)bh * SEQ * 64;
    const size_t vgbase = (size_t)bh * 32 * 4096;
    const int q0 = qtile * 128 + w4 * 32;
    const int kt0 = hk * 16;            // this half's first kv tile

    // staging: 512 slots of 16B per 64x64 tile, spread over this half's
    // 256 threads; thread tt stages slots tt and tt+256.
    int goff[2];
    #pragma unroll
    for (int c = 0; c < 2; ++c) {
        int s = c*256 + tt;
        int row = s >> 3, ks = s & 7;
        goff[c] = row*64 + ((ks ^ (row & 7)) << 3);
    }
    // LDS dest for chunk c: element c*2048 + w4*512 within [hk][buf]

    int foff[4][2];
    #pragma unroll
    for (int nt = 0; nt < 4; ++nt)
        #pragma unroll
        for (int kf = 0; kf < 2; ++kf) {
            int frow = nt*16 + ln;
            foff[nt][kf] = frow*64 + (((kf*4 + g4) ^ (frow & 7)) << 3);
        }

    // Q fragments for BOTH q-tiles (B-operand of swapped QK^T)
    bf16x8 qf0[2], qf1[2];
    #pragma unroll
    for (int kf = 0; kf < 2; ++kf) {
        qf0[kf] = *(const bf16x8*)&Q[base + (size_t)(q0 + ln)*64      + kf*32 + g4*8];
        qf1[kf] = *(const bf16x8*)&Q[base + (size_t)(q0 + 16 + ln)*64 + kf*32 + g4*8];
    }

    bf16x8 ones;
    #pragma unroll
    for (int i = 0; i < 8; ++i) ones[i] = (short)0x3F80;   // bf16 1.0

    f32x4 oacc0[4], oacc1[4];
    #pragma unroll
    for (int i = 0; i < 4; ++i) {
        oacc0[i] = (f32x4){0.f, 0.f, 0.f, 0.f};
        oacc1[i] = (f32x4){0.f, 0.f, 0.f, 0.f};
    }
    f32x4 lacc0 = (f32x4){0.f, 0.f, 0.f, 0.f};
    f32x4 lacc1 = (f32x4){0.f, 0.f, 0.f, 0.f};

    // prologue: stage this half's tile kt0 into buf 0
    #pragma unroll
    for (int c = 0; c < 2; ++c) {
        gload16(&K [base   + (size_t)kt0*4096 + goff[c]], &Kls[hk][0][c*2048 + w4*512]);
        gload16(&Vg[vgbase + (size_t)kt0*4096 + goff[c]], &Vls[hk][0][c*2048 + w4*512]);
    }
    __syncthreads();

    for (int kt2 = 0; kt2 < 8; ++kt2) {
        #pragma unroll
        for (int pb = 0; pb < 2; ++pb) {
            const int kt = kt2*2 + pb;
            if (kt < 15) {   // issue next tile's async loads into other buffer
                #pragma unroll
                for (int c = 0; c < 2; ++c) {
                    gload16(&K [base   + (size_t)(kt0+kt+1)*4096 + goff[c]],
                            &Kls[hk][pb^1][c*2048 + w4*512]);
                    gload16(&Vg[vgbase + (size_t)(kt0+kt+1)*4096 + goff[c]],
                            &Vls[hk][pb^1][c*2048 + w4*512]);
                }
            }
            const u16* Ks  = Kls[hk][pb];
            const u16* Vts = Vls[hk][pb];

            // QK^T for both q-tiles, each K fragment read once
            f32x4 s0[4], s1[4];
            #pragma unroll
            for (int nt = 0; nt < 4; ++nt) {
                s0[nt] = (f32x4){0.f, 0.f, 0.f, 0.f};
                s1[nt] = (f32x4){0.f, 0.f, 0.f, 0.f};
            }
            __builtin_amdgcn_s_setprio(1);
            #pragma unroll
            for (int nt = 0; nt < 4; ++nt)
                #pragma unroll
                for (int kf = 0; kf < 2; ++kf) {
                    bf16x8 kfr = *(const bf16x8*)&Ks[foff[nt][kf]];
                    s0[nt] = __builtin_amdgcn_mfma_f32_16x16x32_bf16(kfr, qf0[kf], s0[nt], 0, 0, 0);
                    s1[nt] = __builtin_amdgcn_mfma_f32_16x16x32_bf16(kfr, qf1[kf], s1[nt], 0, 0, 0);
                }
            __builtin_amdgcn_s_setprio(0);

            // softmax, fixed base m = 0 (r14-verified)
            #pragma unroll
            for (int nt = 0; nt < 4; ++nt)
                #pragma unroll
                for (int r = 0; r < 4; ++r) {
                    s0[nt][r] = fexp2(s0[nt][r]);
                    s1[nt][r] = fexp2(s1[nt][r]);
                }

            union PU { u32 w[4]; bf16x8 v; } a0, a1, b0, b1;
            asm("v_cvt_pk_bf16_f32 %0, %1, %2" : "=v"(a0.w[0]) : "v"(s0[0][0]), "v"(s0[0][1]));
            asm("v_cvt_pk_bf16_f32 %0, %1, %2" : "=v"(a0.w[1]) : "v"(s0[0][2]), "v"(s0[0][3]));
            asm("v_cvt_pk_bf16_f32 %0, %1, %2" : "=v"(a0.w[2]) : "v"(s0[2][0]), "v"(s0[2][1]));
            asm("v_cvt_pk_bf16_f32 %0, %1, %2" : "=v"(a0.w[3]) : "v"(s0[2][2]), "v"(s0[2][3]));
            asm("v_cvt_pk_bf16_f32 %0, %1, %2" : "=v"(a1.w[0]) : "v"(s0[1][0]), "v"(s0[1][1]));
            asm("v_cvt_pk_bf16_f32 %0, %1, %2" : "=v"(a1.w[1]) : "v"(s0[1][2]), "v"(s0[1][3]));
            asm("v_cvt_pk_bf16_f32 %0, %1, %2" : "=v"(a1.w[2]) : "v"(s0[3][0]), "v"(s0[3][1]));
            asm("v_cvt_pk_bf16_f32 %0, %1, %2" : "=v"(a1.w[3]) : "v"(s0[3][2]), "v"(s0[3][3]));
            asm("v_cvt_pk_bf16_f32 %0, %1, %2" : "=v"(b0.w[0]) : "v"(s1[0][0]), "v"(s1[0][1]));
            asm("v_cvt_pk_bf16_f32 %0, %1, %2" : "=v"(b0.w[1]) : "v"(s1[0][2]), "v"(s1[0][3]));
            asm("v_cvt_pk_bf16_f32 %0, %1, %2" : "=v"(b0.w[2]) : "v"(s1[2][0]), "v"(s1[2][1]));
            asm("v_cvt_pk_bf16_f32 %0, %1, %2" : "=v"(b0.w[3]) : "v"(s1[2][2]), "v"(s1[2][3]));
            asm("v_cvt_pk_bf16_f32 %0, %1, %2" : "=v"(b1.w[0]) : "v"(s1[1][0]), "v"(s1[1][1]));
            asm("v_cvt_pk_bf16_f32 %0, %1, %2" : "=v"(b1.w[1]) : "v"(s1[1][2]), "v"(s1[1][3]));
            asm("v_cvt_pk_bf16_f32 %0, %1, %2" : "=v"(b1.w[2]) : "v"(s1[3][0]), "v"(s1[3][1]));
            asm("v_cvt_pk_bf16_f32 %0, %1, %2" : "=v"(b1.w[3]) : "v"(s1[3][2]), "v"(s1[3][3]));
            bf16x8 pf0[2] = { a0.v, a1.v };
            bf16x8 pf1[2] = { b0.v, b1.v };

            // PV for both q-tiles, each V fragment read once; + l-sums
            __builtin_amdgcn_s_setprio(1);
            #pragma unroll
            for (int dt = 0; dt < 4; ++dt)
                #pragma unroll
                for (int kf = 0; kf < 2; ++kf) {
                    bf16x8 vfr = *(const bf16x8*)&Vts[foff[dt][kf]];
                    oacc0[dt] = __builtin_amdgcn_mfma_f32_16x16x32_bf16(pf0[kf], vfr, oacc0[dt], 0, 0, 0);
                    oacc1[dt] = __builtin_amdgcn_mfma_f32_16x16x32_bf16(pf1[kf], vfr, oacc1[dt], 0, 0, 0);
                }
            #pragma unroll
            for (int kf = 0; kf < 2; ++kf) {
                lacc0 = __builtin_amdgcn_mfma_f32_16x16x32_bf16(pf0[kf], ones, lacc0, 0, 0, 0);
                lacc1 = __builtin_amdgcn_mfma_f32_16x16x32_bf16(pf1[kf], ones, lacc1, 0, 0, 0);
            }
            __builtin_amdgcn_s_setprio(0);

            __syncthreads();   // drains my async loads; publishes tile kt+1
        }
    }

    // ---- in-block kv-merge (fixed-base softmax => partials add exactly) ----
    // Last loop barrier guarantees all LDS reads done -> safe to repurpose.
    float* mO = (float*)(&Kls[0][0][0]);   // 32 KB: [w4][qt][dt][lane] f32x4
    float* mL = (float*)(&Vls[0][0][0]);   // 8 KB:  [w4][qt][lane]     f32x4
    if (hk == 1) {
        #pragma unroll
        for (int dt = 0; dt < 4; ++dt) {
            *(f32x4*)&mO[(((w4*2 + 0)*4 + dt)*64 + lane)*4] = oacc0[dt];
            *(f32x4*)&mO[(((w4*2 + 1)*4 + dt)*64 + lane)*4] = oacc1[dt];
        }
        *(f32x4*)&mL[((w4*2 + 0)*64 + lane)*4] = lacc0;
        *(f32x4*)&mL[((w4*2 + 1)*64 + lane)*4] = lacc1;
    }
    __syncthreads();
    if (hk == 0) {
        #pragma unroll
        for (int dt = 0; dt < 4; ++dt) {
            oacc0[dt] += *(const f32x4*)&mO[(((w4*2 + 0)*4 + dt)*64 + lane)*4];
            oacc1[dt] += *(const f32x4*)&mO[(((w4*2 + 1)*4 + dt)*64 + lane)*4];
        }
        lacc0 += *(const f32x4*)&mL[((w4*2 + 0)*64 + lane)*4];
        lacc1 += *(const f32x4*)&mL[((w4*2 + 1)*64 + lane)*4];

        #pragma unroll
        for (int r = 0; r < 4; ++r) {
            float inv0 = 1.f / lacc0[r];
            float inv1 = 1.f / lacc1[r];
            size_t row0 = base + (size_t)(q0 + g4*4 + r)*64;
            size_t row1 = base + (size_t)(q0 + 16 + g4*4 + r)*64;
            #pragma unroll
            for (int dt = 0; dt < 4; ++dt) {
                ctx[row0 + dt*16 + ln] = f2bf(oacc0[dt][r] * inv0);
                ctx[row1 + dt*16 + ln] = f2bf(oacc1[dt][r] * inv1);
            }
        }
    }
}

// ---------------------------------------------------------------------------
// Kernel 3: MFMA output projection (flat-reshape A — round-4 lesson;
// async gload16 double-buffered staging — round-15 verified).
// Round 23: 64x64 tiles, grid (64,16) = 1024 blocks = 4/CU (was 128x64,
// 2/CU). 4 independent barrier domains per CU hide the per-kt drain; LDS
// 32KB. Staging/swizzle contract identical: LDS slot s holds logical
// (row = s>>3, ks^(row&7)); fragment reads use the same XOR formula.
// Wave (wid) -> 32x32 sub-tile: wr = wid>>1, wc = wid&1; 2x2 frags.
// ---------------------------------------------------------------------------
__global__ __launch_bounds__(256, 4) void oproj_kernel(
    const u16* __restrict__ ctx, const u16* __restrict__ wob_t,
    const float* __restrict__ bo, float* __restrict__ out)
{
    __shared__ u16 Als[2][64*64];    // [buf][m][k], swizzled via source
    __shared__ u16 Bls[2][64*64];    // [buf][n][k], swizzled via source
    const int t = threadIdx.x;
    const int wid = t >> 6, lane = t & 63;
    const int ln = lane & 15, g4 = lane >> 4;
    const int wr = wid >> 1, wc = wid & 1;
    const int rb = blockIdx.x, cb = blockIdx.y;
    const int m0 = rb * 64;

    // per-thread swizzled GLOBAL offsets; LDS dest linear (slot*8 elems)
    int gA[2], gB[2];
    #pragma unroll
    for (int c = 0; c < 2; ++c) {
        int slot = c*256 + t;               // 512 slots of 16B per 64x64 tile
        int row = slot >> 3, ks = slot & 7;
        gA[c] = row*1024 + ((ks ^ (row & 7)) << 3);   // A: row stride 1024
        gB[c] = row*64   + ((ks ^ (row & 7)) << 3);   // B: contiguous tile
    }
    const u16* actx = ctx + (size_t)m0*1024;
    const u16* bw   = wob_t + (size_t)cb*16*4096;

    f32x4 acc[2][2];
    #pragma unroll
    for (int mf = 0; mf < 2; ++mf)
        #pragma unroll
        for (int nf = 0; nf < 2; ++nf)
            acc[mf][nf] = (f32x4){0.f, 0.f, 0.f, 0.f};

    // prologue: stage kt=0 into buf 0
    #pragma unroll
    for (int c = 0; c < 2; ++c) {
        gload16(&actx[gA[c]], &Als[0][(c*256+t)*8]);
        gload16(&bw[gB[c]],   &Bls[0][(c*256+t)*8]);
    }
    __syncthreads();

    for (int kt2 = 0; kt2 < 8; ++kt2) {
        #pragma unroll
        for (int half = 0; half < 2; ++half) {
            const int kt = kt2*2 + half;
            if (kt < 15) {   // issue kt+1 into the other buffer
                #pragma unroll
                for (int c = 0; c < 2; ++c) {
                    gload16(&actx[(kt+1)*64 + gA[c]],   &Als[half^1][(c*256+t)*8]);
                    gload16(&bw[(kt+1)*4096 + gB[c]],   &Bls[half^1][(c*256+t)*8]);
                }
            }
            const u16* As = Als[half];
            const u16* Bs = Bls[half];

            __builtin_amdgcn_s_setprio(1);
            #pragma unroll
            for (int kf = 0; kf < 2; ++kf) {
                bf16x8 af[2], bfr[2];
                #pragma unroll
                for (int mf = 0; mf < 2; ++mf) {
                    int arow = wr*32 + mf*16 + ln;
                    af[mf] = *(const bf16x8*)&As[arow*64 + (((kf*4 + g4) ^ (arow & 7)) << 3)];
                }
                #pragma unroll
                for (int nf = 0; nf < 2; ++nf) {
                    int brow = wc*32 + nf*16 + ln;
                    bfr[nf] = *(const bf16x8*)&Bs[brow*64 + (((kf*4 + g4) ^ (brow & 7)) << 3)];
                }
                #pragma unroll
                for (int mf = 0; mf < 2; ++mf)
                    #pragma unroll
                    for (int nf = 0; nf < 2; ++nf)
                        acc[mf][nf] = __builtin_amdgcn_mfma_f32_16x16x32_bf16(
                            af[mf], bfr[nf], acc[mf][nf], 0, 0, 0);
            }
            __builtin_amdgcn_s_setprio(0);

            __syncthreads();   // drains my async loads; publishes kt+1
        }
    }

    #pragma unroll
    for (int mf = 0; mf < 2; ++mf)
        #pragma unroll
        for (int r = 0; r < 4; ++r) {
            int m = m0 + wr*32 + mf*16 + g4*4 + r;
            #pragma unroll
            for (int nf = 0; nf < 2; ++nf) {
                int col = cb*64 + wc*32 + nf*16 + ln;
                out[(size_t)m*1024 + col] = acc[mf][nf][r] + bo[col];
            }
        }
}

extern "C" void kernel_launch(void* const* d_in, const int* in_sizes, int n_in,
                              void* d_out, int out_size, void* d_ws, size_t ws_size,
                              hipStream_t stream) {
    (void)in_sizes; (void)n_in; (void)out_size; (void)ws_size;
    const float* x  = (const float*)d_in[0];
    const float* wq = (const float*)d_in[1];
    const float* bq = (const float*)d_in[2];
    const float* wk = (const float*)d_in[3];
    const float* bk = (const float*)d_in[4];
    const float* wv = (const float*)d_in[5];
    const float* bv = (const float*)d_in[6];
    const float* wo = (const float*)d_in[7];
    const float* bo = (const float*)d_in[8];
    float* out = (float*)d_out;

    u16* Qb  = (u16*)d_ws;
    u16* Kb  = Qb + (size_t)NROWS*64;
    u16* Vgb = Kb + (size_t)NROWS*64;
    u16* ctx = Vgb + (size_t)NROWS*64;
    u16* wob_t = ctx + (size_t)NROWS*64;

    qkv_wconv_kernel<<<dim3(1024), 256, 0, stream>>>(
        x, wq, bq, wk, bk, wv, bv, wo, Qb, Kb, Vgb, wob_t);
    attn_kernel<<<dim3(16, 32), 512, 0, stream>>>(Qb, Kb, Vgb, ctx);
    oproj_kernel<<<dim3(64, 16), 256, 0, stream>>>(ctx, wob_t, bo, out);
}